// Round 11
// baseline (238.683 us; speedup 1.0000x reference)
//
#include <hip/hip_runtime.h>

#define DEVI __device__ __forceinline__

typedef __bf16 bf16x8 __attribute__((ext_vector_type(8)));
typedef float f32x4 __attribute__((ext_vector_type(4)));

// ---------- small helpers ----------
DEVI unsigned short f2bf(float f) {
  unsigned u = __builtin_bit_cast(unsigned, f);
  u += 0x7FFFu + ((u >> 16) & 1u);   // RNE
  return (unsigned short)(u >> 16);
}
DEVI float bf2f(unsigned short s) {
  return __builtin_bit_cast(float, ((unsigned)s) << 16);
}
DEVI f32x4 mfma16(bf16x8 a, bf16x8 b, f32x4 c) {
  return __builtin_amdgcn_mfma_f32_16x16x32_bf16(a, b, c, 0, 0, 0);
}
DEVI void gload16(const void* g, void* l) {
  __builtin_amdgcn_global_load_lds(
      (const __attribute__((address_space(1))) void*)g,
      (__attribute__((address_space(3))) void*)l, 16, 0, 0);
}
// LDS fragment read, rows ROWB bytes, XOR-swizzle byte ^= (row&7)<<4
template <int ROWB>
DEVI bf16x8 frag_ld(const char* lds, int row, int kb) {
  int off = row * ROWB + (kb ^ ((row & 7) << 4));
  return __builtin_bit_cast(bf16x8, *(const uint4*)(lds + off));
}

// ---------- fp32 -> bf16 convert ----------
__global__ __launch_bounds__(256) void k_cvt2(const float* __restrict__ a,
                                              unsigned short* __restrict__ oa, int n4a,
                                              const float* __restrict__ b,
                                              unsigned short* __restrict__ ob, int n4b) {
  const int tid = threadIdx.x;
  if (blockIdx.x < 2048) {
    const int chunk = (blockIdx.x & 7) * 256 + (blockIdx.x >> 3);  // bijective [0,2048)
    const int i0 = chunk * 1536;                                   // 1536 float4 = 8 rows
    for (int i = i0 + tid; i < i0 + 1536; i += 256) {
      float4 f = ((const float4*)a)[i];
      ushort4 o;
      o.x = f2bf(f.x); o.y = f2bf(f.y); o.z = f2bf(f.z); o.w = f2bf(f.w);
      ((ushort4*)oa)[i] = o;
    }
  } else {
    for (int i = (blockIdx.x - 2048) * 256 + tid; i < n4b; i += 256 * 256) {
      float4 f = ((const float4*)b)[i];
      ushort4 o;
      o.x = f2bf(f.x); o.y = f2bf(f.y); o.z = f2bf(f.z); o.w = f2bf(f.w);
      ((ushort4*)ob)[i] = o;
    }
  }
}

// ---------- pipelined 128x192 GEMM body (BK=64, 8 waves 2Mx4N, 2 blocks/CU) ----------
// 2 phases per K-tile; counted vmcnt; raw s_barrier; setprio around MFMA.
// MODE 0: qkv = x@wqkv^T, 3 launches x 512 blocks (li_base 0/512/1024), scatter -> qT,kT,vP
// MODE 1: yp  = vP@B_b^T, 1 launch x 512 blocks, LDS-transposed coalesced bf16 -> yp
template <int MODE>
DEVI void gemm_body(char* lds, const unsigned short* __restrict__ A,
                    const unsigned short* __restrict__ B0,
                    unsigned short* __restrict__ o0, unsigned short* __restrict__ o1,
                    unsigned short* __restrict__ o2, int li_base) {
  const int tid = threadIdx.x, l = tid & 63, wid = tid >> 6;
  const int wr = wid >> 2, wc = wid & 3;
  const int xg = blockIdx.x;
  const int NJT = MODE ? 4 : 12;
  const int li = li_base + (xg & 7) * 64 + (xg >> 3);   // 64 blocks per XCD per launch
  const int jt = li % NJT, mt = li / NJT;
  const int m0 = mt * 128, j0 = jt * 192;
  const unsigned short* Bb = MODE ? B0 + (size_t)(m0 >> 10) * 589824 : B0;

  const unsigned short* srcg[4][2];
  int ldso[4][2];
#pragma unroll
  for (int sg = 0; sg < 4; ++sg) {
    const bool isA = (sg == 0) || (sg == 3);
#pragma unroll
    for (int i = 0; i < 2; ++i) {
      int c;
      if (sg == 0)      c = (wid < 4) ? wid : wid + 4;
      else if (sg == 3) c = (wid < 4) ? wid + 4 : wid + 8;
      else if (sg == 1) { int cc = 2 * wid + i; c = (cc >> 2) * 6 + (cc & 3); }
      else              c = (wid >> 1) * 6 + 4 + (wid & 1);
      const int r0 = 8 * c;
      const int r = r0 + (l >> 3);
      const int scol = ((l & 7) ^ (l >> 3)) << 3;
      srcg[sg][i] = (isA ? A + (size_t)(m0 + r) * 768 : Bb + (size_t)(j0 + r) * 768) + scol;
      ldso[sg][i] = (isA ? 0 : 16384) + r0 * 128;
    }
  }
  const int swz = (l & 7) << 4;
  const int uu = (l >> 4) << 4;
  const int c0 = uu ^ swz;
  const int c1 = (64 | uu) ^ swz;
  const int arow = (wr * 64 + (l & 15)) * 128;
  const int brow = 16384 + (wc * 48 + (l & 15)) * 128;

  f32x4 acc[4][3];
#pragma unroll
  for (int i = 0; i < 4; ++i)
#pragma unroll
    for (int j = 0; j < 3; ++j)
#pragma unroll
      for (int e = 0; e < 4; ++e) acc[i][j][e] = 0.f;
  bf16x8 a[2][2], a2[2][2], b01[2][2], b2[2];

#define STAGE1(sg, nxt, ko) \
  gload16(srcg[sg][0] + (ko), lds + (nxt)*40960 + ldso[sg][0])
#define STAGE2(sg, nxt, ko)                                        \
  do {                                                             \
    gload16(srcg[sg][0] + (ko), lds + (nxt)*40960 + ldso[sg][0]);  \
    gload16(srcg[sg][1] + (ko), lds + (nxt)*40960 + ldso[sg][1]);  \
  } while (0)
#define LD128(off) __builtin_bit_cast(bf16x8, *(const uint4*)(cb_ + (off)))

  STAGE1(0, 0, 0); STAGE2(1, 0, 0); STAGE1(2, 0, 0); STAGE1(3, 0, 0);
  asm volatile("s_waitcnt vmcnt(2)" ::: "memory");
  __builtin_amdgcn_s_barrier();

#define KBODY(KT, LASTF)                                                              \
  {                                                                                   \
    const char* cb_ = lds + ((KT) & 1) * 40960;                                       \
    const int nxt = (((KT) & 1) ^ 1);                                                 \
    const int ko = ((KT) + 1) * 64;                                                   \
    /* ---- ph0: read A01 + B01; stage G0' = {S0, S1x2} ---- */                       \
    _Pragma("unroll") for (int mf = 0; mf < 2; ++mf) {                                \
      a[mf][0] = LD128(arow + mf * 2048 + c0);                                        \
      a[mf][1] = LD128(arow + mf * 2048 + c1);                                        \
    }                                                                                 \
    _Pragma("unroll") for (int nf = 0; nf < 2; ++nf) {                                \
      b01[nf][0] = LD128(brow + nf * 2048 + c0);                                      \
      b01[nf][1] = LD128(brow + nf * 2048 + c1);                                      \
    }                                                                                 \
    if (!(LASTF)) {                                                                   \
      STAGE1(0, nxt, ko); STAGE2(1, nxt, ko);                                         \
      asm volatile("s_waitcnt vmcnt(3)" ::: "memory");                                \
    } else {                                                                          \
      asm volatile("s_waitcnt vmcnt(0)" ::: "memory");                                \
    }                                                                                 \
    __builtin_amdgcn_s_barrier();                                                     \
    __builtin_amdgcn_s_setprio(1);                                                    \
    _Pragma("unroll") for (int mf = 0; mf < 2; ++mf)                                  \
      _Pragma("unroll") for (int nf = 0; nf < 2; ++nf) {                              \
        acc[mf][nf] = mfma16(a[mf][0], b01[nf][0], acc[mf][nf]);                      \
        acc[mf][nf] = mfma16(a[mf][1], b01[nf][1], acc[mf][nf]);                      \
      }                                                                               \
    __builtin_amdgcn_s_setprio(0);                                                    \
    /* ---- ph1: read B2 + A23 (separate regs); stage G1' = {S2, S3} ---- */          \
    b2[0] = LD128(brow + 2 * 2048 + c0);                                              \
    b2[1] = LD128(brow + 2 * 2048 + c1);                                              \
    _Pragma("unroll") for (int mf = 0; mf < 2; ++mf) {                                \
      a2[mf][0] = LD128(arow + (mf + 2) * 2048 + c0);                                 \
      a2[mf][1] = LD128(arow + (mf + 2) * 2048 + c1);                                 \
    }                                                                                 \
    if (!(LASTF)) {                                                                   \
      STAGE1(2, nxt, ko); STAGE1(3, nxt, ko);                                        \
      asm volatile("s_waitcnt vmcnt(2)" ::: "memory");                                \
    }                                                                                 \
    __builtin_amdgcn_s_barrier();                                                     \
    __builtin_amdgcn_s_setprio(1);                                                    \
    _Pragma("unroll") for (int mf = 0; mf < 2; ++mf) {                                \
      acc[mf][2] = mfma16(a[mf][0], b2[0], acc[mf][2]);                               \
      acc[mf][2] = mfma16(a[mf][1], b2[1], acc[mf][2]);                               \
    }                                                                                 \
    _Pragma("unroll") for (int mf = 0; mf < 2; ++mf)                                  \
      _Pragma("unroll") for (int nf = 0; nf < 2; ++nf) {                              \
        acc[mf + 2][nf] = mfma16(a2[mf][0], b01[nf][0], acc[mf + 2][nf]);             \
        acc[mf + 2][nf] = mfma16(a2[mf][1], b01[nf][1], acc[mf + 2][nf]);             \
      }                                                                               \
    _Pragma("unroll") for (int mf = 0; mf < 2; ++mf) {                                \
      acc[mf + 2][2] = mfma16(a2[mf][0], b2[0], acc[mf + 2][2]);                      \
      acc[mf + 2][2] = mfma16(a2[mf][1], b2[1], acc[mf + 2][2]);                      \
    }                                                                                 \
    __builtin_amdgcn_s_setprio(0);                                                    \
  }

#pragma unroll 1
  for (int kt = 0; kt < 11; ++kt) KBODY(kt, false);
  KBODY(11, true);
#undef KBODY
#undef STAGE2
#undef STAGE1
#undef LD128

  if constexpr (MODE == 0) {
    const int s = j0 / 768;
    const int jin0 = (j0 % 768) + wc * 48 + (l & 15);
    const int ntok0 = m0 + wr * 64 + ((l >> 4) << 2);
#pragma unroll
    for (int mf = 0; mf < 4; ++mf) {
      const int nt = ntok0 + mf * 16;
      const int bb = nt >> 10, nin = nt & 1023;
#pragma unroll
      for (int nf = 0; nf < 3; ++nf) {
        const int jj = jin0 + nf * 16;
        const int hh = jj / 96, dd = jj % 96;
        if (s == 2) {
          unsigned short* vp = o2 + (size_t)nt * 768 + jj;
#pragma unroll
          for (int rr = 0; rr < 4; ++rr) vp[rr * 768] = f2bf(acc[mf][nf][rr]);
        } else {
          unsigned short* base = (s == 0) ? o0 : o1;
          ushort4 pk;
          pk.x = f2bf(acc[mf][nf][0]); pk.y = f2bf(acc[mf][nf][1]);
          pk.z = f2bf(acc[mf][nf][2]); pk.w = f2bf(acc[mf][nf][3]);
          *(ushort4*)(base + ((size_t)((bb * 8 + hh) * 96 + dd)) * 1024 + nin) = pk;
        }
      }
    }
  } else {
    // LDS-transpose epilogue -> fully coalesced yp row writes (384B/row).
    // All ds_reads of the staging buffers completed before the last barrier,
    // so the buffer is safe to overwrite; pad rows to 200 ushort (bank shift).
    unsigned short* t = (unsigned short*)lds;   // [128][200]
    const int nl0 = wr * 64 + ((l >> 4) << 2);  // local row in [0,128)
    const int cl0 = wc * 48 + (l & 15);
#pragma unroll
    for (int mf = 0; mf < 4; ++mf)
#pragma unroll
      for (int nf = 0; nf < 3; ++nf)
#pragma unroll
        for (int rr = 0; rr < 4; ++rr)
          t[(nl0 + mf * 16 + rr) * 200 + cl0 + nf * 16] = f2bf(acc[mf][nf][rr]);
    __builtin_amdgcn_s_barrier();
    for (int i2 = tid; i2 < 3072; i2 += 512) {  // 128 rows x 24 chunks of 16B
      int r = i2 / 24, ch = i2 % 24;
      uint4 u = *(const uint4*)(t + r * 200 + ch * 8);
      *(uint4*)(o0 + (size_t)(m0 + r) * 768 + j0 + ch * 8) = u;
    }
  }
}

__global__ __launch_bounds__(512, 4) void kg0_qkv(const unsigned short* __restrict__ A,
                                                  const unsigned short* __restrict__ B0,
                                                  unsigned short* __restrict__ o0,
                                                  unsigned short* __restrict__ o1,
                                                  unsigned short* __restrict__ o2,
                                                  int li_base) {
  __shared__ alignas(16) char lds[81920];
  gemm_body<0>(lds, A, B0, o0, o1, o2, li_base);
}
__global__ __launch_bounds__(512, 4) void kg1_proj(const unsigned short* __restrict__ A,
                                                   const unsigned short* __restrict__ B0,
                                                   unsigned short* __restrict__ o0) {
  __shared__ alignas(16) char lds[81920];
  gemm_body<1>(lds, A, B0, o0, nullptr, nullptr, 0);
}

// ---------- A' = q^T k; scale 1/(|q||k|temp); softmax; write P^T ----------
DEVI float ssq8(uint4 u) {
  unsigned a[4] = {u.x, u.y, u.z, u.w};
  float s = 0.f;
#pragma unroll
  for (int i = 0; i < 4; ++i) {
    float lo = __builtin_bit_cast(float, a[i] << 16);
    float hi = __builtin_bit_cast(float, a[i] & 0xFFFF0000u);
    s += lo * lo + hi * hi;
  }
  return s;
}

__global__ __launch_bounds__(256) void k_attn(const unsigned short* __restrict__ qT,
                                              const unsigned short* __restrict__ kT,
                                              const float* __restrict__ temp,
                                              unsigned short* __restrict__ PT) {
  __shared__ alignas(16) char lQK[2][24576];   // per buf: q [96][64] @0, k @12288 (swizzled)
  __shared__ float lA[96 * 96];
  __shared__ float lrq[96], lrk[96];
  const int blk = blockIdx.x, tid = threadIdx.x, lane = tid & 63, wid = tid >> 6;
  const int idx = blk >> 3;
  const int bb = (blk & 7) * 2 + (idx >> 3);
  const int hh = idx & 7;
  const int bh = bb * 8 + hh;
  const float invt = 1.f / temp[hh];
  const int wr = wid >> 1, wc = wid & 1;
  const unsigned short* qb = qT + (size_t)bh * 96 * 1024;
  const unsigned short* kb = kT + (size_t)bh * 96 * 1024;

  const unsigned short* srcp[6];
  int dsto[6];
#pragma unroll
  for (int i = 0; i < 6; ++i) {
    int cid = wid * 6 + i;          // 24 chunks: 12 q + 12 k
    bool isK = cid >= 12;
    int c = isK ? cid - 12 : cid;
    int p = c * 1024 + lane * 16;
    int r = p >> 7, cb = p & 127;
    int cbs = cb ^ ((r & 7) << 4);
    srcp[i] = (isK ? kb : qb) + (size_t)r * 1024 + (cbs >> 1);
    dsto[i] = (isK ? 12288 : 0) + c * 1024;
  }

  // issue tile 0 stage, then overlap norms compute with its latency
#pragma unroll
  for (int i = 0; i < 6; ++i) gload16(srcp[i], lQK[0] + dsto[i]);

  for (int row = wid; row < 192; row += 4) {
    const unsigned short* src = (row < 96) ? qb + (size_t)row * 1024
                                           : kb + (size_t)(row - 96) * 1024;
    const uint4* p = (const uint4*)src + lane * 2;
    float s = ssq8(p[0]) + ssq8(p[1]);
#pragma unroll
    for (int off = 32; off; off >>= 1) s += __shfl_xor(s, off, 64);
    if (lane == 0) {
      float r = 1.f / fmaxf(sqrtf(s), 1e-12f);
      if (row < 96) lrq[row] = r;
      else          lrk[row - 96] = r;
    }
  }

  f32x4 acc[3][3];
#pragma unroll
  for (int i = 0; i < 3; ++i)
#pragma unroll
    for (int j = 0; j < 3; ++j)
#pragma unroll
      for (int e = 0; e < 4; ++e) acc[i][j][e] = 0.f;

  asm volatile("s_waitcnt vmcnt(0)" ::: "memory");
  __builtin_amdgcn_s_barrier();

#pragma unroll 1
  for (int kt = 0; kt < 16; ++kt) {
    const char* bq = lQK[kt & 1];
    if (kt < 15) {
      char* nb = lQK[(kt + 1) & 1];
      const int ko = (kt + 1) * 64;
#pragma unroll
      for (int i = 0; i < 6; ++i) gload16(srcp[i] + ko, nb + dsto[i]);
    }
#pragma unroll
    for (int ks = 0; ks < 2; ++ks) {
      const int kb2 = ks * 64 + ((lane >> 4) << 4);
      bf16x8 af[3], bfv[3];
#pragma unroll
      for (int mb = 0; mb < 3; ++mb) af[mb] = frag_ld<128>(bq, wr * 48 + mb * 16 + (lane & 15), kb2);
#pragma unroll
      for (int nb2 = 0; nb2 < 3; ++nb2) bfv[nb2] = frag_ld<128>(bq + 12288, wc * 48 + nb2 * 16 + (lane & 15), kb2);
#pragma unroll
      for (int mb = 0; mb < 3; ++mb)
#pragma unroll
        for (int nb2 = 0; nb2 < 3; ++nb2) acc[mb][nb2] = mfma16(af[mb], bfv[nb2], acc[mb][nb2]);
    }
    asm volatile("s_waitcnt vmcnt(0)" ::: "memory");
    __builtin_amdgcn_s_barrier();
  }

  const int rb = wr * 48 + ((lane >> 4) << 2);
  const int eb = wc * 48 + (lane & 15);
#pragma unroll
  for (int mb = 0; mb < 3; ++mb)
#pragma unroll
    for (int nb = 0; nb < 3; ++nb) {
      int e = eb + nb * 16;
#pragma unroll
      for (int rr = 0; rr < 4; ++rr) {
        int d = rb + mb * 16 + rr;
        lA[d * 96 + e] = acc[mb][nb][rr] * lrq[d] * lrk[e] * invt;
      }
    }
  __syncthreads();
  for (int d = wid; d < 96; d += 4) {
    float v0 = lA[d * 96 + lane];
    float v1 = (lane < 32) ? lA[d * 96 + 64 + lane] : -3.0e38f;
    float mx = fmaxf(v0, v1);
#pragma unroll
    for (int off = 32; off; off >>= 1) mx = fmaxf(mx, __shfl_xor(mx, off, 64));
    float p0 = __expf(v0 - mx);
    float p1 = (lane < 32) ? __expf(v1 - mx) : 0.f;
    float ssum = p0 + p1;
#pragma unroll
    for (int off = 32; off; off >>= 1) ssum += __shfl_xor(ssum, off, 64);
    float rs = 1.f / ssum;
    PT[((size_t)bh * 96 + lane) * 96 + d] = f2bf(p0 * rs);
    if (lane < 32) PT[((size_t)bh * 96 + 64 + lane) * 96 + d] = f2bf(p1 * rs);
  }
}

// ---------- B_b[(h,e), c] pre-contraction: B_h = P_h^T @ W_h^T ----------
__global__ __launch_bounds__(256) void k_prep(const unsigned short* __restrict__ PT,
                                              const float* __restrict__ wproj,
                                              unsigned short* __restrict__ B_all) {
  __shared__ alignas(16) char pl[19968 + 39936];   // lPt [96][104] | lW [192][104]
  unsigned short* lPt = (unsigned short*)pl;
  unsigned short* lW  = (unsigned short*)(pl + 19968);
  unsigned short* tr  = lW;                        // aliased after MFMA ([192][100])
  const int blk = blockIdx.x;
  const int idx = blk >> 3;
  const int b = (blk & 7) * 2 + (idx >> 5);
  const int h = (idx >> 2) & 7, cq = idx & 3;
  const int tid = threadIdx.x, l = tid & 63, wid = tid >> 6;
  const int wr = wid >> 1, wc = wid & 1;

  const unsigned short* pt = PT + (size_t)(b * 8 + h) * 96 * 96;
  for (int i2 = tid; i2 < 1152; i2 += 256) {
    int r = i2 / 12, ch = i2 % 12;
    *(uint4*)(lPt + r * 104 + ch * 8) = *(const uint4*)(pt + r * 96 + ch * 8);
  }
  for (int i2 = tid; i2 < 4608; i2 += 256) {
    int r = i2 / 24, ch = i2 % 24;
    float4 f = *(const float4*)(wproj + (size_t)(cq * 192 + r) * 768 + h * 96 + ch * 4);
    ushort4 o;
    o.x = f2bf(f.x); o.y = f2bf(f.y); o.z = f2bf(f.z); o.w = f2bf(f.w);
    *(ushort4*)(lW + r * 104 + ch * 4) = o;
  }
  __syncthreads();

  f32x4 acc[3][6];
#pragma unroll
  for (int i = 0; i < 3; ++i)
#pragma unroll
    for (int j = 0; j < 6; ++j)
#pragma unroll
      for (int e = 0; e < 4; ++e) acc[i][j][e] = 0.f;

#pragma unroll
  for (int ks = 0; ks < 3; ++ks) {
    const int kof = ks * 32 + ((l >> 4) << 3);
    bf16x8 af[3], bv[6];
#pragma unroll
    for (int mb = 0; mb < 3; ++mb)
      af[mb] = __builtin_bit_cast(bf16x8, *(const uint4*)(lPt + (wr * 48 + mb * 16 + (l & 15)) * 104 + kof));
#pragma unroll
    for (int nb = 0; nb < 6; ++nb)
      bv[nb] = __builtin_bit_cast(bf16x8, *(const uint4*)(lW + (wc * 96 + nb * 16 + (l & 15)) * 104 + kof));
#pragma unroll
    for (int mb = 0; mb < 3; ++mb)
#pragma unroll
      for (int nb = 0; nb < 6; ++nb) acc[mb][nb] = mfma16(af[mb], bv[nb], acc[mb][nb]);
  }

  __syncthreads();                 // all lW reads done; safe to alias as tr
  const int e0 = wr * 48 + ((l >> 4) << 2);
  const int cl0 = wc * 96 + (l & 15);
#pragma unroll
  for (int mb = 0; mb < 3; ++mb)
#pragma unroll
    for (int nb = 0; nb < 6; ++nb) {
      ushort4 pk;
      pk.x = f2bf(acc[mb][nb][0]); pk.y = f2bf(acc[mb][nb][1]);
      pk.z = f2bf(acc[mb][nb][2]); pk.w = f2bf(acc[mb][nb][3]);
      *(ushort4*)(tr + (cl0 + nb * 16) * 100 + e0 + mb * 16) = pk;
    }
  __syncthreads();
  for (int i2 = tid; i2 < 2304; i2 += 256) {
    int r = i2 / 12, ch = i2 % 12;
    uint4 u = *(const uint4*)(tr + r * 100 + ch * 8);
    *(uint4*)(B_all + ((size_t)(b * 768) + cq * 192 + r) * 768 + h * 96 + ch * 8) = u;
  }
}

// ---------- final: y = yp(bf16) + 0.1*dwconv3x3(xb bf16); LayerNorm ----------
__global__ __launch_bounds__(256) void k_final(const unsigned short* __restrict__ yp,
                                               const unsigned short* __restrict__ xb16,
                                               const float* __restrict__ cw,
                                               const float* __restrict__ gamma,
                                               const float* __restrict__ beta,
                                               float* __restrict__ out) {
  const int wid = threadIdx.x >> 6, lane = threadIdx.x & 63;
  const int m = (blockIdx.x & 7) * 2048 + (blockIdx.x >> 3) * 4 + wid;  // token id
  const int bb = m >> 10, n = m & 1023, yy = n >> 5, xx = n & 31;
  const unsigned short* xb = xb16 + (size_t)bb * 1024 * 768;

  float yv[3][4];
#pragma unroll
  for (int g = 0; g < 3; ++g) {
    const int c = g * 256 + lane * 4;
    float w36[36];
    const float4* wp = (const float4*)(cw + (size_t)c * 9);
#pragma unroll
    for (int i = 0; i < 9; ++i) *(float4*)(w36 + i * 4) = wp[i];

    float a0 = 0.f, a1 = 0.f, a2 = 0.f, a3 = 0.f;
#pragma unroll
    for (int dy = -1; dy <= 1; ++dy) {
      int ny = yy + dy;
      if ((unsigned)ny < 32u) {
#pragma unroll
        for (int dx = -1; dx <= 1; ++dx) {
          int nx = xx + dx;
          if ((unsigned)nx < 32u) {
            ushort4 v = *(const ushort4*)(xb + (size_t)(ny * 32 + nx) * 768 + c);
            const int j = (dy + 1) * 3 + (dx + 1);
            a0 += w36[0 * 9 + j] * bf2f(v.x);
            a1 += w36[1 * 9 + j] * bf2f(v.y);
            a2 += w36[2 * 9 + j] * bf2f(v.z);
            a3 += w36[3 * 9 + j] * bf2f(v.w);
          }
        }
      }
    }
    ushort4 f = *(const ushort4*)(yp + (size_t)m * 768 + c);
    yv[g][0] = bf2f(f.x) + 0.1f * a0;
    yv[g][1] = bf2f(f.y) + 0.1f * a1;
    yv[g][2] = bf2f(f.z) + 0.1f * a2;
    yv[g][3] = bf2f(f.w) + 0.1f * a3;
  }

  float s1 = 0.f, s2 = 0.f;
#pragma unroll
  for (int g = 0; g < 3; ++g)
#pragma unroll
    for (int e = 0; e < 4; ++e) { s1 += yv[g][e]; s2 += yv[g][e] * yv[g][e]; }
#pragma unroll
  for (int off = 32; off; off >>= 1) {
    s1 += __shfl_xor(s1, off, 64);
    s2 += __shfl_xor(s2, off, 64);
  }
  const float mu = s1 * (1.f / 768.f);
  const float var = s2 * (1.f / 768.f) - mu * mu;
  const float rs = rsqrtf(var + 1e-5f);

#pragma unroll
  for (int g = 0; g < 3; ++g) {
    const int c = g * 256 + lane * 4;
    float4 gm = *(const float4*)(gamma + c);
    float4 bt = *(const float4*)(beta + c);
    float4 o;
    o.x = (yv[g][0] - mu) * rs * gm.x + bt.x;
    o.y = (yv[g][1] - mu) * rs * gm.y + bt.y;
    o.z = (yv[g][2] - mu) * rs * gm.z + bt.z;
    o.w = (yv[g][3] - mu) * rs * gm.w + bt.w;
    *(float4*)(out + (size_t)m * 768 + c) = o;
  }
}

// ---------- host ----------
extern "C" void kernel_launch(void* const* d_in, const int* in_sizes, int n_in,
                              void* d_out, int out_size, void* d_ws, size_t ws_size,
                              hipStream_t stream) {
  const float* x     = (const float*)d_in[0];
  const float* wqkv  = (const float*)d_in[1];
  const float* wproj = (const float*)d_in[2];
  const float* temp  = (const float*)d_in[3];
  const float* cw    = (const float*)d_in[4];
  const float* gamma = (const float*)d_in[5];
  const float* beta  = (const float*)d_in[6];
  float* out = (float*)d_out;
  char* ws = (char*)d_ws;

  // workspace layout (~107 MiB; aliased regions are stream-ordered dead)
  unsigned short* xb    = (unsigned short*)(ws);               // 25165824 B (x bf16; live to k_final)
  unsigned short* wqb   = (unsigned short*)(ws + 25165824);    // 3538944 (dead after kg0)
  unsigned short* qT    = (unsigned short*)(ws + 28704768);    // 25165824 (dead after attn)
  unsigned short* yp    = qT;                                  //   alias
  unsigned short* kT    = (unsigned short*)(ws + 53870592);    // 25165824 (dead after attn)
  unsigned short* B_all = kT;                                  //   alias: 16*768*768*2 = 18874368
  unsigned short* vP    = (unsigned short*)(ws + 79036416);    // 25165824
  unsigned short* PT    = (unsigned short*)(ws + 104202240);   // 2359296

  k_cvt2<<<dim3(2304), dim3(256), 0, stream>>>(x, xb, 16384 * 768 / 4,
                                               wqkv, wqb, 2304 * 768 / 4);
  kg0_qkv<<<dim3(512), dim3(512), 0, stream>>>(xb, wqb, qT, kT, vP, 0);
  kg0_qkv<<<dim3(512), dim3(512), 0, stream>>>(xb, wqb, qT, kT, vP, 512);
  kg0_qkv<<<dim3(512), dim3(512), 0, stream>>>(xb, wqb, qT, kT, vP, 1024);
  k_attn<<<dim3(128), dim3(256), 0, stream>>>(qT, kT, temp, PT);
  k_prep<<<dim3(512), dim3(256), 0, stream>>>(PT, wproj, B_all);
  kg1_proj<<<dim3(512), dim3(512), 0, stream>>>(vP, B_all, yp);
  k_final<<<dim3(4096), dim3(256), 0, stream>>>(yp, xb, cw, gamma, beta, out);
}

// Round 12
// 209.780 us; speedup vs baseline: 1.1378x; 1.1378x over previous
//
#include <hip/hip_runtime.h>

#define DEVI __device__ __forceinline__

typedef __bf16 bf16x8 __attribute__((ext_vector_type(8)));
typedef float f32x4 __attribute__((ext_vector_type(4)));

// ---------- small helpers ----------
DEVI unsigned short f2bf(float f) {
  unsigned u = __builtin_bit_cast(unsigned, f);
  u += 0x7FFFu + ((u >> 16) & 1u);   // RNE
  return (unsigned short)(u >> 16);
}
DEVI float bf2f(unsigned short s) {
  return __builtin_bit_cast(float, ((unsigned)s) << 16);
}
DEVI f32x4 mfma16(bf16x8 a, bf16x8 b, f32x4 c) {
  return __builtin_amdgcn_mfma_f32_16x16x32_bf16(a, b, c, 0, 0, 0);
}
DEVI void gload16(const void* g, void* l) {
  __builtin_amdgcn_global_load_lds(
      (const __attribute__((address_space(1))) void*)g,
      (__attribute__((address_space(3))) void*)l, 16, 0, 0);
}
// LDS fragment read, rows ROWB bytes, XOR-swizzle byte ^= (row&7)<<4
template <int ROWB>
DEVI bf16x8 frag_ld(const char* lds, int row, int kb) {
  int off = row * ROWB + (kb ^ ((row & 7) << 4));
  return __builtin_bit_cast(bf16x8, *(const uint4*)(lds + off));
}

// ---------- fp32 -> bf16 convert ----------
__global__ __launch_bounds__(256) void k_cvt2(const float* __restrict__ a,
                                              unsigned short* __restrict__ oa, int n4a,
                                              const float* __restrict__ b,
                                              unsigned short* __restrict__ ob, int n4b) {
  const int tid = threadIdx.x;
  if (blockIdx.x < 2048) {
    const int chunk = (blockIdx.x & 7) * 256 + (blockIdx.x >> 3);  // bijective [0,2048)
    const int i0 = chunk * 1536;                                   // 1536 float4 = 8 rows
    for (int i = i0 + tid; i < i0 + 1536; i += 256) {
      float4 f = ((const float4*)a)[i];
      ushort4 o;
      o.x = f2bf(f.x); o.y = f2bf(f.y); o.z = f2bf(f.z); o.w = f2bf(f.w);
      ((ushort4*)oa)[i] = o;
    }
  } else {
    for (int i = (blockIdx.x - 2048) * 256 + tid; i < n4b; i += 256 * 256) {
      float4 f = ((const float4*)b)[i];
      ushort4 o;
      o.x = f2bf(f.x); o.y = f2bf(f.y); o.z = f2bf(f.z); o.w = f2bf(f.w);
      ((ushort4*)ob)[i] = o;
    }
  }
}

// ---------- pipelined 128x192 GEMM body (BK=64, 8 waves 2Mx4N, 2 blocks/CU) ----------
// MODE 0: qkv = x@wqkv^T, grid 1536 (128mt x 12jt = 3 rounds), scatter -> qT,kT,vP
//         + per-column sum-of-squares atomics into ns (q:[0], k:[+12288]).
// MODE 1: yp  = vP@B_b^T, grid 512, LDS-transposed coalesced bf16 -> yp
template <int MODE>
DEVI void gemm_body(char* lds, const unsigned short* __restrict__ A,
                    const unsigned short* __restrict__ B0,
                    unsigned short* __restrict__ o0, unsigned short* __restrict__ o1,
                    unsigned short* __restrict__ o2, float* __restrict__ ns) {
  const int tid = threadIdx.x, l = tid & 63, wid = tid >> 6;
  const int wr = wid >> 2, wc = wid & 3;
  const int xg = blockIdx.x;
  const int CPX = MODE ? 64 : 192;
  const int NJT = MODE ? 4 : 12;
  const int li = (xg & 7) * CPX + (xg >> 3);
  const int jt = li % NJT, mt = li / NJT;
  const int m0 = mt * 128, j0 = jt * 192;
  const unsigned short* Bb = MODE ? B0 + (size_t)(m0 >> 10) * 589824 : B0;

  const unsigned short* srcg[4][2];
  int ldso[4][2];
#pragma unroll
  for (int sg = 0; sg < 4; ++sg) {
    const bool isA = (sg == 0) || (sg == 3);
#pragma unroll
    for (int i = 0; i < 2; ++i) {
      int c;
      if (sg == 0)      c = (wid < 4) ? wid : wid + 4;
      else if (sg == 3) c = (wid < 4) ? wid + 4 : wid + 8;
      else if (sg == 1) { int cc = 2 * wid + i; c = (cc >> 2) * 6 + (cc & 3); }
      else              c = (wid >> 1) * 6 + 4 + (wid & 1);
      const int r0 = 8 * c;
      const int r = r0 + (l >> 3);
      const int scol = ((l & 7) ^ (l >> 3)) << 3;
      srcg[sg][i] = (isA ? A + (size_t)(m0 + r) * 768 : Bb + (size_t)(j0 + r) * 768) + scol;
      ldso[sg][i] = (isA ? 0 : 16384) + r0 * 128;
    }
  }
  const int swz = (l & 7) << 4;
  const int uu = (l >> 4) << 4;
  const int c0 = uu ^ swz;
  const int c1 = (64 | uu) ^ swz;
  const int arow = (wr * 64 + (l & 15)) * 128;
  const int brow = 16384 + (wc * 48 + (l & 15)) * 128;

  f32x4 acc[4][3];
#pragma unroll
  for (int i = 0; i < 4; ++i)
#pragma unroll
    for (int j = 0; j < 3; ++j)
#pragma unroll
      for (int e = 0; e < 4; ++e) acc[i][j][e] = 0.f;
  bf16x8 a[2][2], a2[2][2], b01[2][2], b2[2];

#define STAGE1(sg, nxt, ko) \
  gload16(srcg[sg][0] + (ko), lds + (nxt)*40960 + ldso[sg][0])
#define STAGE2(sg, nxt, ko)                                        \
  do {                                                             \
    gload16(srcg[sg][0] + (ko), lds + (nxt)*40960 + ldso[sg][0]);  \
    gload16(srcg[sg][1] + (ko), lds + (nxt)*40960 + ldso[sg][1]);  \
  } while (0)
#define LD128(off) __builtin_bit_cast(bf16x8, *(const uint4*)(cb_ + (off)))

  STAGE1(0, 0, 0); STAGE2(1, 0, 0); STAGE1(2, 0, 0); STAGE1(3, 0, 0);
  asm volatile("s_waitcnt vmcnt(2)" ::: "memory");
  __builtin_amdgcn_s_barrier();

#define KBODY(KT, LASTF)                                                              \
  {                                                                                   \
    const char* cb_ = lds + ((KT) & 1) * 40960;                                       \
    const int nxt = (((KT) & 1) ^ 1);                                                 \
    const int ko = ((KT) + 1) * 64;                                                   \
    _Pragma("unroll") for (int mf = 0; mf < 2; ++mf) {                                \
      a[mf][0] = LD128(arow + mf * 2048 + c0);                                        \
      a[mf][1] = LD128(arow + mf * 2048 + c1);                                        \
    }                                                                                 \
    _Pragma("unroll") for (int nf = 0; nf < 2; ++nf) {                                \
      b01[nf][0] = LD128(brow + nf * 2048 + c0);                                      \
      b01[nf][1] = LD128(brow + nf * 2048 + c1);                                      \
    }                                                                                 \
    if (!(LASTF)) {                                                                   \
      STAGE1(0, nxt, ko); STAGE2(1, nxt, ko);                                         \
      asm volatile("s_waitcnt vmcnt(3)" ::: "memory");                                \
    } else {                                                                          \
      asm volatile("s_waitcnt vmcnt(0)" ::: "memory");                                \
    }                                                                                 \
    __builtin_amdgcn_s_barrier();                                                     \
    __builtin_amdgcn_s_setprio(1);                                                    \
    _Pragma("unroll") for (int mf = 0; mf < 2; ++mf)                                  \
      _Pragma("unroll") for (int nf = 0; nf < 2; ++nf) {                              \
        acc[mf][nf] = mfma16(a[mf][0], b01[nf][0], acc[mf][nf]);                      \
        acc[mf][nf] = mfma16(a[mf][1], b01[nf][1], acc[mf][nf]);                      \
      }                                                                               \
    __builtin_amdgcn_s_setprio(0);                                                    \
    b2[0] = LD128(brow + 2 * 2048 + c0);                                              \
    b2[1] = LD128(brow + 2 * 2048 + c1);                                              \
    _Pragma("unroll") for (int mf = 0; mf < 2; ++mf) {                                \
      a2[mf][0] = LD128(arow + (mf + 2) * 2048 + c0);                                 \
      a2[mf][1] = LD128(arow + (mf + 2) * 2048 + c1);                                 \
    }                                                                                 \
    if (!(LASTF)) {                                                                   \
      STAGE1(2, nxt, ko); STAGE1(3, nxt, ko);                                         \
      asm volatile("s_waitcnt vmcnt(2)" ::: "memory");                                \
    }                                                                                 \
    __builtin_amdgcn_s_barrier();                                                     \
    __builtin_amdgcn_s_setprio(1);                                                    \
    _Pragma("unroll") for (int mf = 0; mf < 2; ++mf) {                                \
      acc[mf][2] = mfma16(a[mf][0], b2[0], acc[mf][2]);                               \
      acc[mf][2] = mfma16(a[mf][1], b2[1], acc[mf][2]);                               \
    }                                                                                 \
    _Pragma("unroll") for (int mf = 0; mf < 2; ++mf)                                  \
      _Pragma("unroll") for (int nf = 0; nf < 2; ++nf) {                              \
        acc[mf + 2][nf] = mfma16(a2[mf][0], b01[nf][0], acc[mf + 2][nf]);             \
        acc[mf + 2][nf] = mfma16(a2[mf][1], b01[nf][1], acc[mf + 2][nf]);             \
      }                                                                               \
    _Pragma("unroll") for (int mf = 0; mf < 2; ++mf) {                                \
      acc[mf + 2][2] = mfma16(a2[mf][0], b2[0], acc[mf + 2][2]);                      \
      acc[mf + 2][2] = mfma16(a2[mf][1], b2[1], acc[mf + 2][2]);                      \
    }                                                                                 \
    __builtin_amdgcn_s_setprio(0);                                                    \
  }

#pragma unroll 1
  for (int kt = 0; kt < 11; ++kt) KBODY(kt, false);
  KBODY(11, true);
#undef KBODY
#undef STAGE2
#undef STAGE1
#undef LD128

  if constexpr (MODE == 0) {
    const int s = j0 / 768;
    const int jin0 = (j0 % 768) + wc * 48 + (l & 15);
    const int ntok0 = m0 + wr * 64 + ((l >> 4) << 2);
    const int bb = m0 >> 10;   // 128-token tile lies in one batch
#pragma unroll
    for (int mf = 0; mf < 4; ++mf) {
      const int nt = ntok0 + mf * 16;
      const int nin = nt & 1023;
#pragma unroll
      for (int nf = 0; nf < 3; ++nf) {
        const int jj = jin0 + nf * 16;
        const int hh = jj / 96, dd = jj % 96;
        if (s == 2) {
          unsigned short* vp = o2 + (size_t)nt * 768 + jj;
#pragma unroll
          for (int rr = 0; rr < 4; ++rr) vp[rr * 768] = f2bf(acc[mf][nf][rr]);
        } else {
          unsigned short* base = (s == 0) ? o0 : o1;
          ushort4 pk;
          pk.x = f2bf(acc[mf][nf][0]); pk.y = f2bf(acc[mf][nf][1]);
          pk.z = f2bf(acc[mf][nf][2]); pk.w = f2bf(acc[mf][nf][3]);
          *(ushort4*)(base + ((size_t)((bb * 8 + hh) * 96 + dd)) * 1024 + nin) = pk;
        }
      }
    }
    // token-dim sum-of-squares for q/k norms (fp32, pre-rounding)
    if (s < 2) {
      float* nsp = (s == 0) ? ns : ns + 12288;
#pragma unroll
      for (int nf = 0; nf < 3; ++nf) {
        float ss = 0.f;
#pragma unroll
        for (int mf = 0; mf < 4; ++mf)
#pragma unroll
          for (int rr = 0; rr < 4; ++rr) ss += acc[mf][nf][rr] * acc[mf][nf][rr];
        ss += __shfl_xor(ss, 16, 64);
        ss += __shfl_xor(ss, 32, 64);
        if ((l >> 4) == 0) {
          const int jj = jin0 + nf * 16;
          atomicAdd(&nsp[(bb * 8 + jj / 96) * 96 + jj % 96], ss);
        }
      }
    }
  } else {
    // LDS-transpose epilogue -> coalesced yp row writes (384B/row).
    unsigned short* t = (unsigned short*)lds;   // [128][200]
    const int nl0 = wr * 64 + ((l >> 4) << 2);
    const int cl0 = wc * 48 + (l & 15);
#pragma unroll
    for (int mf = 0; mf < 4; ++mf)
#pragma unroll
      for (int nf = 0; nf < 3; ++nf)
#pragma unroll
        for (int rr = 0; rr < 4; ++rr)
          t[(nl0 + mf * 16 + rr) * 200 + cl0 + nf * 16] = f2bf(acc[mf][nf][rr]);
    __builtin_amdgcn_s_barrier();
    for (int i2 = tid; i2 < 3072; i2 += 512) {
      int r = i2 / 24, ch = i2 % 24;
      uint4 u = *(const uint4*)(t + r * 200 + ch * 8);
      *(uint4*)(o0 + (size_t)(m0 + r) * 768 + j0 + ch * 8) = u;
    }
  }
}

__global__ __launch_bounds__(512, 4) void kg0_qkv(const unsigned short* __restrict__ A,
                                                  const unsigned short* __restrict__ B0,
                                                  unsigned short* __restrict__ o0,
                                                  unsigned short* __restrict__ o1,
                                                  unsigned short* __restrict__ o2,
                                                  float* __restrict__ ns) {
  __shared__ alignas(16) char lds[81920];
  gemm_body<0>(lds, A, B0, o0, o1, o2, ns);
}
__global__ __launch_bounds__(512, 4) void kg1_proj(const unsigned short* __restrict__ A,
                                                   const unsigned short* __restrict__ B0,
                                                   unsigned short* __restrict__ o0) {
  __shared__ alignas(16) char lds[81920];
  gemm_body<1>(lds, A, B0, o0, nullptr, nullptr, nullptr);
}

// ---------- k_qk: partial A' = q^T k over a K-half -> PA fp32 ----------
// grid 256 = (bh, kh); block 256 (4 waves 2x2); LDS 48KB dbuf.
__global__ __launch_bounds__(256) void k_qk(const unsigned short* __restrict__ qT,
                                            const unsigned short* __restrict__ kT,
                                            float* __restrict__ PA) {
  __shared__ alignas(16) char lQK[2][24576];   // per buf: q [96][64] @0, k @12288
  const int blk = blockIdx.x, tid = threadIdx.x, lane = tid & 63, wid = tid >> 6;
  const int bh = blk >> 1, kh = blk & 1;
  const int wr = wid >> 1, wc = wid & 1;
  const unsigned short* qb = qT + (size_t)bh * 96 * 1024 + kh * 512;
  const unsigned short* kb = kT + (size_t)bh * 96 * 1024 + kh * 512;

  const unsigned short* srcp[6];
  int dsto[6];
#pragma unroll
  for (int i = 0; i < 6; ++i) {
    int cid = wid * 6 + i;          // 24 chunks: 12 q + 12 k
    bool isK = cid >= 12;
    int c = isK ? cid - 12 : cid;
    int p = c * 1024 + lane * 16;
    int r = p >> 7, cb = p & 127;
    int cbs = cb ^ ((r & 7) << 4);
    srcp[i] = (isK ? kb : qb) + (size_t)r * 1024 + (cbs >> 1);
    dsto[i] = (isK ? 12288 : 0) + c * 1024;
  }

  f32x4 acc[3][3];
#pragma unroll
  for (int i = 0; i < 3; ++i)
#pragma unroll
    for (int j = 0; j < 3; ++j)
#pragma unroll
      for (int e = 0; e < 4; ++e) acc[i][j][e] = 0.f;

#pragma unroll
  for (int i = 0; i < 6; ++i) gload16(srcp[i], lQK[0] + dsto[i]);
  asm volatile("s_waitcnt vmcnt(0)" ::: "memory");
  __builtin_amdgcn_s_barrier();

#pragma unroll 1
  for (int kt = 0; kt < 8; ++kt) {
    const char* bq = lQK[kt & 1];
    if (kt < 7) {
      char* nb = lQK[(kt + 1) & 1];
      const int ko = (kt + 1) * 64;
#pragma unroll
      for (int i = 0; i < 6; ++i) gload16(srcp[i] + ko, nb + dsto[i]);
    }
#pragma unroll
    for (int ks = 0; ks < 2; ++ks) {
      const int kb2 = ks * 64 + ((lane >> 4) << 4);
      bf16x8 af[3], bfv[3];
#pragma unroll
      for (int mb = 0; mb < 3; ++mb) af[mb] = frag_ld<128>(bq, wr * 48 + mb * 16 + (lane & 15), kb2);
#pragma unroll
      for (int nb2 = 0; nb2 < 3; ++nb2) bfv[nb2] = frag_ld<128>(bq + 12288, wc * 48 + nb2 * 16 + (lane & 15), kb2);
#pragma unroll
      for (int mb = 0; mb < 3; ++mb)
#pragma unroll
        for (int nb2 = 0; nb2 < 3; ++nb2) acc[mb][nb2] = mfma16(af[mb], bfv[nb2], acc[mb][nb2]);
    }
    asm volatile("s_waitcnt vmcnt(0)" ::: "memory");
    __builtin_amdgcn_s_barrier();
  }

  float* pa = PA + (size_t)(bh * 2 + kh) * 9216;
  const int rb = wr * 48 + ((lane >> 4) << 2);
  const int eb = wc * 48 + (lane & 15);
#pragma unroll
  for (int mb = 0; mb < 3; ++mb)
#pragma unroll
    for (int nb = 0; nb < 3; ++nb)
#pragma unroll
      for (int rr = 0; rr < 4; ++rr)
        pa[(rb + mb * 16 + rr) * 96 + eb + nb * 16] = acc[mb][nb][rr];
}

// ---------- k_soft: sum partials, scale, softmax, write PT coalesced ----------
__global__ __launch_bounds__(256) void k_soft(const float* __restrict__ PA,
                                              const float* __restrict__ ns,
                                              const float* __restrict__ temp,
                                              unsigned short* __restrict__ PT) {
  __shared__ float aa[9216];               // [d][e] fp32
  __shared__ unsigned short ptb[96 * 104]; // [e][d] padded
  __shared__ float lrq[96], lrk[96];
  const int bh = blockIdx.x, tid = threadIdx.x, lane = tid & 63, wid = tid >> 6;
  const float invt = 1.f / temp[bh & 7];
  if (tid < 96)       lrq[tid] = 1.f / fmaxf(sqrtf(ns[bh * 96 + tid]), 1e-12f);
  else if (tid < 192) lrk[tid - 96] = 1.f / fmaxf(sqrtf(ns[12288 + bh * 96 + tid - 96]), 1e-12f);

  const float4* pp = (const float4*)(PA + (size_t)bh * 2 * 9216);
  for (int i = tid; i < 2304; i += 256) {
    float4 x0 = pp[i], x1 = pp[i + 2304];
    float4 r;
    r.x = x0.x + x1.x; r.y = x0.y + x1.y; r.z = x0.z + x1.z; r.w = x0.w + x1.w;
    ((float4*)aa)[i] = r;
  }
  __syncthreads();

  for (int d = wid; d < 96; d += 4) {
    float v0 = aa[d * 96 + lane] * lrq[d] * lrk[lane] * invt;
    float v1 = (lane < 32) ? aa[d * 96 + 64 + lane] * lrq[d] * lrk[64 + lane] * invt : -3.0e38f;
    float mx = fmaxf(v0, v1);
#pragma unroll
    for (int off = 32; off; off >>= 1) mx = fmaxf(mx, __shfl_xor(mx, off, 64));
    float p0 = __expf(v0 - mx);
    float p1 = (lane < 32) ? __expf(v1 - mx) : 0.f;
    float ssum = p0 + p1;
#pragma unroll
    for (int off = 32; off; off >>= 1) ssum += __shfl_xor(ssum, off, 64);
    float rs = 1.f / ssum;
    ptb[lane * 104 + d] = f2bf(p0 * rs);
    if (lane < 32) ptb[(64 + lane) * 104 + d] = f2bf(p1 * rs);
  }
  __syncthreads();
  for (int i = tid; i < 1152; i += 256) {   // 96 rows x 12 uint4
    int r = i / 12, ch = i % 12;
    *(uint4*)(PT + (size_t)bh * 9216 + r * 96 + ch * 8) = *(const uint4*)(ptb + r * 104 + ch * 8);
  }
}

// ---------- B_b[(h,e), c] pre-contraction: B_h = P_h^T @ W_h^T ----------
__global__ __launch_bounds__(256) void k_prep(const unsigned short* __restrict__ PT,
                                              const float* __restrict__ wproj,
                                              unsigned short* __restrict__ B_all) {
  __shared__ alignas(16) char pl[19968 + 39936];   // lPt [96][104] | lW [192][104]
  unsigned short* lPt = (unsigned short*)pl;
  unsigned short* lW  = (unsigned short*)(pl + 19968);
  unsigned short* tr  = lW;                        // aliased after MFMA ([192][100])
  const int blk = blockIdx.x;
  const int idx = blk >> 3;
  const int b = (blk & 7) * 2 + (idx >> 5);
  const int h = (idx >> 2) & 7, cq = idx & 3;
  const int tid = threadIdx.x, l = tid & 63, wid = tid >> 6;
  const int wr = wid >> 1, wc = wid & 1;

  const unsigned short* pt = PT + (size_t)(b * 8 + h) * 96 * 96;
  for (int i2 = tid; i2 < 1152; i2 += 256) {
    int r = i2 / 12, ch = i2 % 12;
    *(uint4*)(lPt + r * 104 + ch * 8) = *(const uint4*)(pt + r * 96 + ch * 8);
  }
  for (int i2 = tid; i2 < 4608; i2 += 256) {
    int r = i2 / 24, ch = i2 % 24;
    float4 f = *(const float4*)(wproj + (size_t)(cq * 192 + r) * 768 + h * 96 + ch * 4);
    ushort4 o;
    o.x = f2bf(f.x); o.y = f2bf(f.y); o.z = f2bf(f.z); o.w = f2bf(f.w);
    *(ushort4*)(lW + r * 104 + ch * 4) = o;
  }
  __syncthreads();

  f32x4 acc[3][6];
#pragma unroll
  for (int i = 0; i < 3; ++i)
#pragma unroll
    for (int j = 0; j < 6; ++j)
#pragma unroll
      for (int e = 0; e < 4; ++e) acc[i][j][e] = 0.f;

#pragma unroll
  for (int ks = 0; ks < 3; ++ks) {
    const int kof = ks * 32 + ((l >> 4) << 3);
    bf16x8 af[3], bv[6];
#pragma unroll
    for (int mb = 0; mb < 3; ++mb)
      af[mb] = __builtin_bit_cast(bf16x8, *(const uint4*)(lPt + (wr * 48 + mb * 16 + (l & 15)) * 104 + kof));
#pragma unroll
    for (int nb = 0; nb < 6; ++nb)
      bv[nb] = __builtin_bit_cast(bf16x8, *(const uint4*)(lW + (wc * 96 + nb * 16 + (l & 15)) * 104 + kof));
#pragma unroll
    for (int mb = 0; mb < 3; ++mb)
#pragma unroll
      for (int nb = 0; nb < 6; ++nb) acc[mb][nb] = mfma16(af[mb], bv[nb], acc[mb][nb]);
  }

  __syncthreads();
  const int e0 = wr * 48 + ((l >> 4) << 2);
  const int cl0 = wc * 96 + (l & 15);
#pragma unroll
  for (int mb = 0; mb < 3; ++mb)
#pragma unroll
    for (int nb = 0; nb < 6; ++nb) {
      ushort4 pk;
      pk.x = f2bf(acc[mb][nb][0]); pk.y = f2bf(acc[mb][nb][1]);
      pk.z = f2bf(acc[mb][nb][2]); pk.w = f2bf(acc[mb][nb][3]);
      *(ushort4*)(tr + (cl0 + nb * 16) * 100 + e0 + mb * 16) = pk;
    }
  __syncthreads();
  for (int i2 = tid; i2 < 2304; i2 += 256) {
    int r = i2 / 12, ch = i2 % 12;
    uint4 u = *(const uint4*)(tr + r * 100 + ch * 8);
    *(uint4*)(B_all + ((size_t)(b * 768) + cq * 192 + r) * 768 + h * 96 + ch * 8) = u;
  }
}

// ---------- final: y = yp(bf16) + 0.1*dwconv3x3(xb bf16); LayerNorm ----------
__global__ __launch_bounds__(256) void k_final(const unsigned short* __restrict__ yp,
                                               const unsigned short* __restrict__ xb16,
                                               const float* __restrict__ cw,
                                               const float* __restrict__ gamma,
                                               const float* __restrict__ beta,
                                               float* __restrict__ out) {
  const int wid = threadIdx.x >> 6, lane = threadIdx.x & 63;
  const int m = (blockIdx.x & 7) * 2048 + (blockIdx.x >> 3) * 4 + wid;  // token id
  const int bb = m >> 10, n = m & 1023, yy = n >> 5, xx = n & 31;
  const unsigned short* xb = xb16 + (size_t)bb * 1024 * 768;

  float yv[3][4];
#pragma unroll
  for (int g = 0; g < 3; ++g) {
    const int c = g * 256 + lane * 4;
    float w36[36];
    const float4* wp = (const float4*)(cw + (size_t)c * 9);
#pragma unroll
    for (int i = 0; i < 9; ++i) *(float4*)(w36 + i * 4) = wp[i];

    float a0 = 0.f, a1 = 0.f, a2 = 0.f, a3 = 0.f;
#pragma unroll
    for (int dy = -1; dy <= 1; ++dy) {
      int ny = yy + dy;
      if ((unsigned)ny < 32u) {
#pragma unroll
        for (int dx = -1; dx <= 1; ++dx) {
          int nx = xx + dx;
          if ((unsigned)nx < 32u) {
            ushort4 v = *(const ushort4*)(xb + (size_t)(ny * 32 + nx) * 768 + c);
            const int j = (dy + 1) * 3 + (dx + 1);
            a0 += w36[0 * 9 + j] * bf2f(v.x);
            a1 += w36[1 * 9 + j] * bf2f(v.y);
            a2 += w36[2 * 9 + j] * bf2f(v.z);
            a3 += w36[3 * 9 + j] * bf2f(v.w);
          }
        }
      }
    }
    ushort4 f = *(const ushort4*)(yp + (size_t)m * 768 + c);
    yv[g][0] = bf2f(f.x) + 0.1f * a0;
    yv[g][1] = bf2f(f.y) + 0.1f * a1;
    yv[g][2] = bf2f(f.z) + 0.1f * a2;
    yv[g][3] = bf2f(f.w) + 0.1f * a3;
  }

  float s1 = 0.f, s2 = 0.f;
#pragma unroll
  for (int g = 0; g < 3; ++g)
#pragma unroll
    for (int e = 0; e < 4; ++e) { s1 += yv[g][e]; s2 += yv[g][e] * yv[g][e]; }
#pragma unroll
  for (int off = 32; off; off >>= 1) {
    s1 += __shfl_xor(s1, off, 64);
    s2 += __shfl_xor(s2, off, 64);
  }
  const float mu = s1 * (1.f / 768.f);
  const float var = s2 * (1.f / 768.f) - mu * mu;
  const float rs = rsqrtf(var + 1e-5f);

#pragma unroll
  for (int g = 0; g < 3; ++g) {
    const int c = g * 256 + lane * 4;
    float4 gm = *(const float4*)(gamma + c);
    float4 bt = *(const float4*)(beta + c);
    float4 o;
    o.x = (yv[g][0] - mu) * rs * gm.x + bt.x;
    o.y = (yv[g][1] - mu) * rs * gm.y + bt.y;
    o.z = (yv[g][2] - mu) * rs * gm.z + bt.z;
    o.w = (yv[g][3] - mu) * rs * gm.w + bt.w;
    *(float4*)(out + (size_t)m * 768 + c) = o;
  }
}

// ---------- host ----------
extern "C" void kernel_launch(void* const* d_in, const int* in_sizes, int n_in,
                              void* d_out, int out_size, void* d_ws, size_t ws_size,
                              hipStream_t stream) {
  const float* x     = (const float*)d_in[0];
  const float* wqkv  = (const float*)d_in[1];
  const float* wproj = (const float*)d_in[2];
  const float* temp  = (const float*)d_in[3];
  const float* cw    = (const float*)d_in[4];
  const float* gamma = (const float*)d_in[5];
  const float* beta  = (const float*)d_in[6];
  float* out = (float*)d_out;
  char* ws = (char*)d_ws;

  // workspace layout (~113.7 MiB; aliased regions are stream-ordered dead)
  unsigned short* xb    = (unsigned short*)(ws);               // 25165824 (live to k_final)
  unsigned short* wqb   = (unsigned short*)(ws + 25165824);    // 3538944 (dead after kg0)
  unsigned short* PT    = wqb;                                 //   alias: 2359296 (soft->prep)
  unsigned short* qT    = (unsigned short*)(ws + 28704768);    // 25165824 (dead after k_qk)
  unsigned short* yp    = qT;                                  //   alias (kg1->final)
  unsigned short* kT    = (unsigned short*)(ws + 53870592);    // 25165824 (dead after k_qk)
  unsigned short* B_all = kT;                                  //   alias (prep->kg1)
  unsigned short* vP    = (unsigned short*)(ws + 79036416);    // 25165824 (kg0->kg1)
  float* ns             = (float*)(ws + 104202240);            // 98304 (kg0 atomics -> soft)
  float* PA             = (float*)(ws + 104300544);            // 9437184 (k_qk -> soft)

  hipMemsetAsync(ns, 0, 98304, stream);
  k_cvt2<<<dim3(2304), dim3(256), 0, stream>>>(x, xb, 16384 * 768 / 4,
                                               wqkv, wqb, 2304 * 768 / 4);
  kg0_qkv<<<dim3(1536), dim3(512), 0, stream>>>(xb, wqb, qT, kT, vP, ns);
  k_qk<<<dim3(256), dim3(256), 0, stream>>>(qT, kT, PA);
  k_soft<<<dim3(128), dim3(256), 0, stream>>>(PA, ns, temp, PT);
  k_prep<<<dim3(512), dim3(256), 0, stream>>>(PT, wproj, B_all);
  kg1_proj<<<dim3(512), dim3(512), 0, stream>>>(vP, B_all, yp);
  k_final<<<dim3(4096), dim3(256), 0, stream>>>(yp, xb, cw, gamma, beta, out);
}

// Round 13
// 203.464 us; speedup vs baseline: 1.1731x; 1.0310x over previous
//
#include <hip/hip_runtime.h>

#define DEVI __device__ __forceinline__

typedef __bf16 bf16x8 __attribute__((ext_vector_type(8)));
typedef float f32x4 __attribute__((ext_vector_type(4)));

// ---------- small helpers ----------
DEVI unsigned short f2bf(float f) {
  unsigned u = __builtin_bit_cast(unsigned, f);
  u += 0x7FFFu + ((u >> 16) & 1u);   // RNE
  return (unsigned short)(u >> 16);
}
DEVI float bf2f(unsigned short s) {
  return __builtin_bit_cast(float, ((unsigned)s) << 16);
}
DEVI f32x4 mfma16(bf16x8 a, bf16x8 b, f32x4 c) {
  return __builtin_amdgcn_mfma_f32_16x16x32_bf16(a, b, c, 0, 0, 0);
}
DEVI void gload16(const void* g, void* l) {
  __builtin_amdgcn_global_load_lds(
      (const __attribute__((address_space(1))) void*)g,
      (__attribute__((address_space(3))) void*)l, 16, 0, 0);
}
// LDS fragment read, rows ROWB bytes, XOR-swizzle byte ^= (row&7)<<4
template <int ROWB>
DEVI bf16x8 frag_ld(const char* lds, int row, int kb) {
  int off = row * ROWB + (kb ^ ((row & 7) << 4));
  return __builtin_bit_cast(bf16x8, *(const uint4*)(lds + off));
}
DEVI float ssq8(uint4 u) {
  unsigned a[4] = {u.x, u.y, u.z, u.w};
  float s = 0.f;
#pragma unroll
  for (int i = 0; i < 4; ++i) {
    float lo = __builtin_bit_cast(float, a[i] << 16);
    float hi = __builtin_bit_cast(float, a[i] & 0xFFFF0000u);
    s += lo * lo + hi * hi;
  }
  return s;
}
DEVI float ssqbf8(bf16x8 v) { return ssq8(__builtin_bit_cast(uint4, v)); }

// ---------- fp32 -> bf16 convert ----------
__global__ __launch_bounds__(256) void k_cvt2(const float* __restrict__ a,
                                              unsigned short* __restrict__ oa, int n4a,
                                              const float* __restrict__ b,
                                              unsigned short* __restrict__ ob, int n4b) {
  const int tid = threadIdx.x;
  if (blockIdx.x < 2048) {
    const int chunk = (blockIdx.x & 7) * 256 + (blockIdx.x >> 3);  // bijective [0,2048)
    const int i0 = chunk * 1536;                                   // 1536 float4 = 8 rows
    for (int i = i0 + tid; i < i0 + 1536; i += 256) {
      float4 f = ((const float4*)a)[i];
      ushort4 o;
      o.x = f2bf(f.x); o.y = f2bf(f.y); o.z = f2bf(f.z); o.w = f2bf(f.w);
      ((ushort4*)oa)[i] = o;
    }
  } else {
    for (int i = (blockIdx.x - 2048) * 256 + tid; i < n4b; i += 256 * 256) {
      float4 f = ((const float4*)b)[i];
      ushort4 o;
      o.x = f2bf(f.x); o.y = f2bf(f.y); o.z = f2bf(f.z); o.w = f2bf(f.w);
      ((ushort4*)ob)[i] = o;
    }
  }
}

// ---------- pipelined 128x192 GEMM body (BK=64, 8 waves 2Mx4N, 2 blocks/CU) ----------
// MODE 0: qkv = x@wqkv^T, grid 1536 (128mt x 12jt = 3 rounds), scatter -> qT,kT,vP
// MODE 1: yp  = vP@B_b^T, grid 512, LDS-transposed coalesced bf16 -> yp
template <int MODE>
DEVI void gemm_body(char* lds, const unsigned short* __restrict__ A,
                    const unsigned short* __restrict__ B0,
                    unsigned short* __restrict__ o0, unsigned short* __restrict__ o1,
                    unsigned short* __restrict__ o2) {
  const int tid = threadIdx.x, l = tid & 63, wid = tid >> 6;
  const int wr = wid >> 2, wc = wid & 3;
  const int xg = blockIdx.x;
  const int CPX = MODE ? 64 : 192;
  const int NJT = MODE ? 4 : 12;
  const int li = (xg & 7) * CPX + (xg >> 3);
  const int jt = li % NJT, mt = li / NJT;
  const int m0 = mt * 128, j0 = jt * 192;
  const unsigned short* Bb = MODE ? B0 + (size_t)(m0 >> 10) * 589824 : B0;

  const unsigned short* srcg[4][2];
  int ldso[4][2];
#pragma unroll
  for (int sg = 0; sg < 4; ++sg) {
    const bool isA = (sg == 0) || (sg == 3);
#pragma unroll
    for (int i = 0; i < 2; ++i) {
      int c;
      if (sg == 0)      c = (wid < 4) ? wid : wid + 4;
      else if (sg == 3) c = (wid < 4) ? wid + 4 : wid + 8;
      else if (sg == 1) { int cc = 2 * wid + i; c = (cc >> 2) * 6 + (cc & 3); }
      else              c = (wid >> 1) * 6 + 4 + (wid & 1);
      const int r0 = 8 * c;
      const int r = r0 + (l >> 3);
      const int scol = ((l & 7) ^ (l >> 3)) << 3;
      srcg[sg][i] = (isA ? A + (size_t)(m0 + r) * 768 : Bb + (size_t)(j0 + r) * 768) + scol;
      ldso[sg][i] = (isA ? 0 : 16384) + r0 * 128;
    }
  }
  const int swz = (l & 7) << 4;
  const int uu = (l >> 4) << 4;
  const int c0 = uu ^ swz;
  const int c1 = (64 | uu) ^ swz;
  const int arow = (wr * 64 + (l & 15)) * 128;
  const int brow = 16384 + (wc * 48 + (l & 15)) * 128;

  f32x4 acc[4][3];
#pragma unroll
  for (int i = 0; i < 4; ++i)
#pragma unroll
    for (int j = 0; j < 3; ++j)
#pragma unroll
      for (int e = 0; e < 4; ++e) acc[i][j][e] = 0.f;
  bf16x8 a[2][2], a2[2][2], b01[2][2], b2[2];

#define STAGE1(sg, nxt, ko) \
  gload16(srcg[sg][0] + (ko), lds + (nxt)*40960 + ldso[sg][0])
#define STAGE2(sg, nxt, ko)                                        \
  do {                                                             \
    gload16(srcg[sg][0] + (ko), lds + (nxt)*40960 + ldso[sg][0]);  \
    gload16(srcg[sg][1] + (ko), lds + (nxt)*40960 + ldso[sg][1]);  \
  } while (0)
#define LD128(off) __builtin_bit_cast(bf16x8, *(const uint4*)(cb_ + (off)))

  STAGE1(0, 0, 0); STAGE2(1, 0, 0); STAGE1(2, 0, 0); STAGE1(3, 0, 0);
  asm volatile("s_waitcnt vmcnt(2)" ::: "memory");
  __builtin_amdgcn_s_barrier();

#define KBODY(KT, LASTF)                                                              \
  {                                                                                   \
    const char* cb_ = lds + ((KT) & 1) * 40960;                                       \
    const int nxt = (((KT) & 1) ^ 1);                                                 \
    const int ko = ((KT) + 1) * 64;                                                   \
    _Pragma("unroll") for (int mf = 0; mf < 2; ++mf) {                                \
      a[mf][0] = LD128(arow + mf * 2048 + c0);                                        \
      a[mf][1] = LD128(arow + mf * 2048 + c1);                                        \
    }                                                                                 \
    _Pragma("unroll") for (int nf = 0; nf < 2; ++nf) {                                \
      b01[nf][0] = LD128(brow + nf * 2048 + c0);                                      \
      b01[nf][1] = LD128(brow + nf * 2048 + c1);                                      \
    }                                                                                 \
    if (!(LASTF)) {                                                                   \
      STAGE1(0, nxt, ko); STAGE2(1, nxt, ko);                                         \
      asm volatile("s_waitcnt vmcnt(3)" ::: "memory");                                \
    } else {                                                                          \
      asm volatile("s_waitcnt vmcnt(0)" ::: "memory");                                \
    }                                                                                 \
    __builtin_amdgcn_s_barrier();                                                     \
    __builtin_amdgcn_s_setprio(1);                                                    \
    _Pragma("unroll") for (int mf = 0; mf < 2; ++mf)                                  \
      _Pragma("unroll") for (int nf = 0; nf < 2; ++nf) {                              \
        acc[mf][nf] = mfma16(a[mf][0], b01[nf][0], acc[mf][nf]);                      \
        acc[mf][nf] = mfma16(a[mf][1], b01[nf][1], acc[mf][nf]);                      \
      }                                                                               \
    __builtin_amdgcn_s_setprio(0);                                                    \
    b2[0] = LD128(brow + 2 * 2048 + c0);                                              \
    b2[1] = LD128(brow + 2 * 2048 + c1);                                              \
    _Pragma("unroll") for (int mf = 0; mf < 2; ++mf) {                                \
      a2[mf][0] = LD128(arow + (mf + 2) * 2048 + c0);                                 \
      a2[mf][1] = LD128(arow + (mf + 2) * 2048 + c1);                                 \
    }                                                                                 \
    if (!(LASTF)) {                                                                   \
      STAGE1(2, nxt, ko); STAGE1(3, nxt, ko);                                        \
      asm volatile("s_waitcnt vmcnt(2)" ::: "memory");                                \
    }                                                                                 \
    __builtin_amdgcn_s_barrier();                                                     \
    __builtin_amdgcn_s_setprio(1);                                                    \
    _Pragma("unroll") for (int mf = 0; mf < 2; ++mf) {                                \
      acc[mf][2] = mfma16(a[mf][0], b2[0], acc[mf][2]);                               \
      acc[mf][2] = mfma16(a[mf][1], b2[1], acc[mf][2]);                               \
    }                                                                                 \
    _Pragma("unroll") for (int mf = 0; mf < 2; ++mf)                                  \
      _Pragma("unroll") for (int nf = 0; nf < 2; ++nf) {                              \
        acc[mf + 2][nf] = mfma16(a2[mf][0], b01[nf][0], acc[mf + 2][nf]);             \
        acc[mf + 2][nf] = mfma16(a2[mf][1], b01[nf][1], acc[mf + 2][nf]);             \
      }                                                                               \
    _Pragma("unroll") for (int mf = 0; mf < 2; ++mf) {                                \
      acc[mf + 2][2] = mfma16(a2[mf][0], b2[0], acc[mf + 2][2]);                      \
      acc[mf + 2][2] = mfma16(a2[mf][1], b2[1], acc[mf + 2][2]);                      \
    }                                                                                 \
    __builtin_amdgcn_s_setprio(0);                                                    \
  }

#pragma unroll 1
  for (int kt = 0; kt < 11; ++kt) KBODY(kt, false);
  KBODY(11, true);
#undef KBODY
#undef STAGE2
#undef STAGE1
#undef LD128

  if constexpr (MODE == 0) {
    const int s = j0 / 768;
    const int jin0 = (j0 % 768) + wc * 48 + (l & 15);
    const int ntok0 = m0 + wr * 64 + ((l >> 4) << 2);
    const int bb = m0 >> 10;
#pragma unroll
    for (int mf = 0; mf < 4; ++mf) {
      const int nt = ntok0 + mf * 16;
      const int nin = nt & 1023;
#pragma unroll
      for (int nf = 0; nf < 3; ++nf) {
        const int jj = jin0 + nf * 16;
        const int hh = jj / 96, dd = jj % 96;
        if (s == 2) {
          unsigned short* vp = o2 + (size_t)nt * 768 + jj;
#pragma unroll
          for (int rr = 0; rr < 4; ++rr) vp[rr * 768] = f2bf(acc[mf][nf][rr]);
        } else {
          unsigned short* base = (s == 0) ? o0 : o1;
          ushort4 pk;
          pk.x = f2bf(acc[mf][nf][0]); pk.y = f2bf(acc[mf][nf][1]);
          pk.z = f2bf(acc[mf][nf][2]); pk.w = f2bf(acc[mf][nf][3]);
          *(ushort4*)(base + ((size_t)((bb * 8 + hh) * 96 + dd)) * 1024 + nin) = pk;
        }
      }
    }
  } else {
    // LDS-transpose epilogue -> coalesced yp row writes (384B/row).
    unsigned short* t = (unsigned short*)lds;   // [128][200]
    const int nl0 = wr * 64 + ((l >> 4) << 2);
    const int cl0 = wc * 48 + (l & 15);
#pragma unroll
    for (int mf = 0; mf < 4; ++mf)
#pragma unroll
      for (int nf = 0; nf < 3; ++nf)
#pragma unroll
        for (int rr = 0; rr < 4; ++rr)
          t[(nl0 + mf * 16 + rr) * 200 + cl0 + nf * 16] = f2bf(acc[mf][nf][rr]);
    __builtin_amdgcn_s_barrier();
    for (int i2 = tid; i2 < 3072; i2 += 512) {
      int r = i2 / 24, ch = i2 % 24;
      uint4 u = *(const uint4*)(t + r * 200 + ch * 8);
      *(uint4*)(o0 + (size_t)(m0 + r) * 768 + j0 + ch * 8) = u;
    }
  }
}

__global__ __launch_bounds__(512, 4) void kg0_qkv(const unsigned short* __restrict__ A,
                                                  const unsigned short* __restrict__ B0,
                                                  unsigned short* __restrict__ o0,
                                                  unsigned short* __restrict__ o1,
                                                  unsigned short* __restrict__ o2) {
  __shared__ alignas(16) char lds[81920];
  gemm_body<0>(lds, A, B0, o0, o1, o2);
}
__global__ __launch_bounds__(512, 4) void kg1_proj(const unsigned short* __restrict__ A,
                                                   const unsigned short* __restrict__ B0,
                                                   unsigned short* __restrict__ o0) {
  __shared__ alignas(16) char lds[81920];
  gemm_body<1>(lds, A, B0, o0, nullptr, nullptr);
}

// ---------- k_qk: partial A' = q^T k over a K-half -> PA fp32; + ssq atomics ----------
// grid 256 = (bh, kh); block 256 (4 waves 2x2); LDS 48KB dbuf.
// ssq: af frags (q) identical across wc -> accumulate on wc==0 waves;
//      bfv frags (k) identical across wr -> accumulate on wr==0 waves.
__global__ __launch_bounds__(256) void k_qk(const unsigned short* __restrict__ qT,
                                            const unsigned short* __restrict__ kT,
                                            float* __restrict__ PA,
                                            float* __restrict__ ns) {
  __shared__ alignas(16) char lQK[2][24576];   // per buf: q [96][64] @0, k @12288
  const int blk = blockIdx.x, tid = threadIdx.x, lane = tid & 63, wid = tid >> 6;
  const int bh = blk >> 1, kh = blk & 1;
  const int wr = wid >> 1, wc = wid & 1;
  const unsigned short* qb = qT + (size_t)bh * 96 * 1024 + kh * 512;
  const unsigned short* kb = kT + (size_t)bh * 96 * 1024 + kh * 512;

  const unsigned short* srcp[6];
  int dsto[6];
#pragma unroll
  for (int i = 0; i < 6; ++i) {
    int cid = wid * 6 + i;          // 24 chunks: 12 q + 12 k
    bool isK = cid >= 12;
    int c = isK ? cid - 12 : cid;
    int p = c * 1024 + lane * 16;
    int r = p >> 7, cb = p & 127;
    int cbs = cb ^ ((r & 7) << 4);
    srcp[i] = (isK ? kb : qb) + (size_t)r * 1024 + (cbs >> 1);
    dsto[i] = (isK ? 12288 : 0) + c * 1024;
  }

  f32x4 acc[3][3];
#pragma unroll
  for (int i = 0; i < 3; ++i)
#pragma unroll
    for (int j = 0; j < 3; ++j)
#pragma unroll
      for (int e = 0; e < 4; ++e) acc[i][j][e] = 0.f;
  float sq[3] = {0.f, 0.f, 0.f}, sk[3] = {0.f, 0.f, 0.f};

#pragma unroll
  for (int i = 0; i < 6; ++i) gload16(srcp[i], lQK[0] + dsto[i]);
  asm volatile("s_waitcnt vmcnt(0)" ::: "memory");
  __builtin_amdgcn_s_barrier();

#pragma unroll 1
  for (int kt = 0; kt < 8; ++kt) {
    const char* bq = lQK[kt & 1];
    if (kt < 7) {
      char* nb = lQK[(kt + 1) & 1];
      const int ko = (kt + 1) * 64;
#pragma unroll
      for (int i = 0; i < 6; ++i) gload16(srcp[i] + ko, nb + dsto[i]);
    }
#pragma unroll
    for (int ks = 0; ks < 2; ++ks) {
      const int kb2 = ks * 64 + ((lane >> 4) << 4);
      bf16x8 af[3], bfv[3];
#pragma unroll
      for (int mb = 0; mb < 3; ++mb) af[mb] = frag_ld<128>(bq, wr * 48 + mb * 16 + (lane & 15), kb2);
#pragma unroll
      for (int nb2 = 0; nb2 < 3; ++nb2) bfv[nb2] = frag_ld<128>(bq + 12288, wc * 48 + nb2 * 16 + (lane & 15), kb2);
      if (wc == 0) {
#pragma unroll
        for (int mb = 0; mb < 3; ++mb) sq[mb] += ssqbf8(af[mb]);
      }
      if (wr == 0) {
#pragma unroll
        for (int nb2 = 0; nb2 < 3; ++nb2) sk[nb2] += ssqbf8(bfv[nb2]);
      }
#pragma unroll
      for (int mb = 0; mb < 3; ++mb)
#pragma unroll
        for (int nb2 = 0; nb2 < 3; ++nb2) acc[mb][nb2] = mfma16(af[mb], bfv[nb2], acc[mb][nb2]);
    }
    asm volatile("s_waitcnt vmcnt(0)" ::: "memory");
    __builtin_amdgcn_s_barrier();
  }

  float* pa = PA + (size_t)(bh * 2 + kh) * 9216;
  const int rb = wr * 48 + ((lane >> 4) << 2);
  const int eb = wc * 48 + (lane & 15);
#pragma unroll
  for (int mb = 0; mb < 3; ++mb)
#pragma unroll
    for (int nb = 0; nb < 3; ++nb)
#pragma unroll
      for (int rr = 0; rr < 4; ++rr)
        pa[(rb + mb * 16 + rr) * 96 + eb + nb * 16] = acc[mb][nb][rr];

  // ssq reduce over k-groups (lane>>4) and atomically accumulate into ns
  if (wc == 0) {
#pragma unroll
    for (int mb = 0; mb < 3; ++mb) {
      float s = sq[mb];
      s += __shfl_xor(s, 16, 64);
      s += __shfl_xor(s, 32, 64);
      if ((lane >> 4) == 0)
        atomicAdd(&ns[bh * 96 + wr * 48 + mb * 16 + (lane & 15)], s);
    }
  }
  if (wr == 0) {
#pragma unroll
    for (int nb2 = 0; nb2 < 3; ++nb2) {
      float s = sk[nb2];
      s += __shfl_xor(s, 16, 64);
      s += __shfl_xor(s, 32, 64);
      if ((lane >> 4) == 0)
        atomicAdd(&ns[12288 + bh * 96 + wc * 48 + nb2 * 16 + (lane & 15)], s);
    }
  }
}

// ---------- fused softmax + B-prep: B_h = softmax(A'_h)^T @ W_h^T ----------
// grid 512 = (b,h,cq); each block re-derives its (b,h) softmax from PA+ns (4x
// redundant, L3-served), result lands in the lPt MFMA operand directly.
__global__ __launch_bounds__(256) void k_prep(const float* __restrict__ PA,
                                              const float* __restrict__ ns,
                                              const float* __restrict__ temp,
                                              const float* __restrict__ wproj,
                                              unsigned short* __restrict__ B_all) {
  __shared__ alignas(16) char pl[19968 + 39936];   // lPt [96][104] | scratch (aa / lW)
  unsigned short* lPt = (unsigned short*)pl;
  float* aa = (float*)(pl + 19968);                // [96][96] fp32 (36864B)
  unsigned short* lW = (unsigned short*)(pl + 19968);  // [192][104] bf16 (39936B)
  unsigned short* tr = lW;                         // aliased after MFMA ([192][100])
  __shared__ float lrq[96], lrk[96];
  const int blk = blockIdx.x;
  const int idx = blk >> 3;
  const int b = (blk & 7) * 2 + (idx >> 5);
  const int h = (idx >> 2) & 7, cq = idx & 3;
  const int bh = b * 8 + h;
  const int tid = threadIdx.x, l = tid & 63, wid = tid >> 6;
  const int wr = wid >> 1, wc = wid & 1;
  const float invt = 1.f / temp[h];

  if (tid < 96)       lrq[tid] = 1.f / fmaxf(sqrtf(ns[bh * 96 + tid]), 1e-12f);
  else if (tid < 192) lrk[tid - 96] = 1.f / fmaxf(sqrtf(ns[12288 + bh * 96 + tid - 96]), 1e-12f);

  const float4* pp = (const float4*)(PA + (size_t)bh * 2 * 9216);
  for (int i = tid; i < 2304; i += 256) {
    float4 x0 = pp[i], x1 = pp[i + 2304];
    float4 r;
    r.x = x0.x + x1.x; r.y = x0.y + x1.y; r.z = x0.z + x1.z; r.w = x0.w + x1.w;
    ((float4*)aa)[i] = r;
  }
  __syncthreads();

  for (int d = wid; d < 96; d += 4) {
    float v0 = aa[d * 96 + l] * lrq[d] * lrk[l] * invt;
    float v1 = (l < 32) ? aa[d * 96 + 64 + l] * lrq[d] * lrk[64 + l] * invt : -3.0e38f;
    float mx = fmaxf(v0, v1);
#pragma unroll
    for (int off = 32; off; off >>= 1) mx = fmaxf(mx, __shfl_xor(mx, off, 64));
    float p0 = __expf(v0 - mx);
    float p1 = (l < 32) ? __expf(v1 - mx) : 0.f;
    float ssum = p0 + p1;
#pragma unroll
    for (int off = 32; off; off >>= 1) ssum += __shfl_xor(ssum, off, 64);
    float rs = 1.f / ssum;
    lPt[l * 104 + d] = f2bf(p0 * rs);                 // lPt[e][d]
    if (l < 32) lPt[(64 + l) * 104 + d] = f2bf(p1 * rs);
  }
  __syncthreads();                 // aa dead; lW may overwrite scratch

  for (int i2 = tid; i2 < 4608; i2 += 256) {
    int r = i2 / 24, ch = i2 % 24;
    float4 f = *(const float4*)(wproj + (size_t)(cq * 192 + r) * 768 + h * 96 + ch * 4);
    ushort4 o;
    o.x = f2bf(f.x); o.y = f2bf(f.y); o.z = f2bf(f.z); o.w = f2bf(f.w);
    *(ushort4*)(lW + r * 104 + ch * 4) = o;
  }
  __syncthreads();

  f32x4 acc[3][6];
#pragma unroll
  for (int i = 0; i < 3; ++i)
#pragma unroll
    for (int j = 0; j < 6; ++j)
#pragma unroll
      for (int e = 0; e < 4; ++e) acc[i][j][e] = 0.f;

#pragma unroll
  for (int ks = 0; ks < 3; ++ks) {
    const int kof = ks * 32 + ((l >> 4) << 3);
    bf16x8 af[3], bv[6];
#pragma unroll
    for (int mb = 0; mb < 3; ++mb)
      af[mb] = __builtin_bit_cast(bf16x8, *(const uint4*)(lPt + (wr * 48 + mb * 16 + (l & 15)) * 104 + kof));
#pragma unroll
    for (int nb = 0; nb < 6; ++nb)
      bv[nb] = __builtin_bit_cast(bf16x8, *(const uint4*)(lW + (wc * 96 + nb * 16 + (l & 15)) * 104 + kof));
#pragma unroll
    for (int mb = 0; mb < 3; ++mb)
#pragma unroll
      for (int nb = 0; nb < 6; ++nb) acc[mb][nb] = mfma16(af[mb], bv[nb], acc[mb][nb]);
  }

  __syncthreads();                 // all lW reads done; safe to alias as tr
  const int e0 = wr * 48 + ((l >> 4) << 2);
  const int cl0 = wc * 96 + (l & 15);
#pragma unroll
  for (int mb = 0; mb < 3; ++mb)
#pragma unroll
    for (int nb = 0; nb < 6; ++nb) {
      ushort4 pk;
      pk.x = f2bf(acc[mb][nb][0]); pk.y = f2bf(acc[mb][nb][1]);
      pk.z = f2bf(acc[mb][nb][2]); pk.w = f2bf(acc[mb][nb][3]);
      *(ushort4*)(tr + (cl0 + nb * 16) * 100 + e0 + mb * 16) = pk;
    }
  __syncthreads();
  for (int i2 = tid; i2 < 2304; i2 += 256) {
    int r = i2 / 12, ch = i2 % 12;
    uint4 u = *(const uint4*)(tr + r * 100 + ch * 8);
    *(uint4*)(B_all + ((size_t)(b * 768) + cq * 192 + r) * 768 + h * 96 + ch * 8) = u;
  }
}

// ---------- final: y = yp(bf16) + 0.1*dwconv3x3(xb bf16); LayerNorm ----------
__global__ __launch_bounds__(256) void k_final(const unsigned short* __restrict__ yp,
                                               const unsigned short* __restrict__ xb16,
                                               const float* __restrict__ cw,
                                               const float* __restrict__ gamma,
                                               const float* __restrict__ beta,
                                               float* __restrict__ out) {
  const int wid = threadIdx.x >> 6, lane = threadIdx.x & 63;
  const int m = (blockIdx.x & 7) * 2048 + (blockIdx.x >> 3) * 4 + wid;  // token id
  const int bb = m >> 10, n = m & 1023, yy = n >> 5, xx = n & 31;
  const unsigned short* xb = xb16 + (size_t)bb * 1024 * 768;

  float yv[3][4];
#pragma unroll
  for (int g = 0; g < 3; ++g) {
    const int c = g * 256 + lane * 4;
    float w36[36];
    const float4* wp = (const float4*)(cw + (size_t)c * 9);
#pragma unroll
    for (int i = 0; i < 9; ++i) *(float4*)(w36 + i * 4) = wp[i];

    float a0 = 0.f, a1 = 0.f, a2 = 0.f, a3 = 0.f;
#pragma unroll
    for (int dy = -1; dy <= 1; ++dy) {
      int ny = yy + dy;
      if ((unsigned)ny < 32u) {
#pragma unroll
        for (int dx = -1; dx <= 1; ++dx) {
          int nx = xx + dx;
          if ((unsigned)nx < 32u) {
            ushort4 v = *(const ushort4*)(xb + (size_t)(ny * 32 + nx) * 768 + c);
            const int j = (dy + 1) * 3 + (dx + 1);
            a0 += w36[0 * 9 + j] * bf2f(v.x);
            a1 += w36[1 * 9 + j] * bf2f(v.y);
            a2 += w36[2 * 9 + j] * bf2f(v.z);
            a3 += w36[3 * 9 + j] * bf2f(v.w);
          }
        }
      }
    }
    ushort4 f = *(const ushort4*)(yp + (size_t)m * 768 + c);
    yv[g][0] = bf2f(f.x) + 0.1f * a0;
    yv[g][1] = bf2f(f.y) + 0.1f * a1;
    yv[g][2] = bf2f(f.z) + 0.1f * a2;
    yv[g][3] = bf2f(f.w) + 0.1f * a3;
  }

  float s1 = 0.f, s2 = 0.f;
#pragma unroll
  for (int g = 0; g < 3; ++g)
#pragma unroll
    for (int e = 0; e < 4; ++e) { s1 += yv[g][e]; s2 += yv[g][e] * yv[g][e]; }
#pragma unroll
  for (int off = 32; off; off >>= 1) {
    s1 += __shfl_xor(s1, off, 64);
    s2 += __shfl_xor(s2, off, 64);
  }
  const float mu = s1 * (1.f / 768.f);
  const float var = s2 * (1.f / 768.f) - mu * mu;
  const float rs = rsqrtf(var + 1e-5f);

#pragma unroll
  for (int g = 0; g < 3; ++g) {
    const int c = g * 256 + lane * 4;
    float4 gm = *(const float4*)(gamma + c);
    float4 bt = *(const float4*)(beta + c);
    float4 o;
    o.x = (yv[g][0] - mu) * rs * gm.x + bt.x;
    o.y = (yv[g][1] - mu) * rs * gm.y + bt.y;
    o.z = (yv[g][2] - mu) * rs * gm.z + bt.z;
    o.w = (yv[g][3] - mu) * rs * gm.w + bt.w;
    *(float4*)(out + (size_t)m * 768 + c) = o;
  }
}

// ---------- host ----------
extern "C" void kernel_launch(void* const* d_in, const int* in_sizes, int n_in,
                              void* d_out, int out_size, void* d_ws, size_t ws_size,
                              hipStream_t stream) {
  const float* x     = (const float*)d_in[0];
  const float* wqkv  = (const float*)d_in[1];
  const float* wproj = (const float*)d_in[2];
  const float* temp  = (const float*)d_in[3];
  const float* cw    = (const float*)d_in[4];
  const float* gamma = (const float*)d_in[5];
  const float* beta  = (const float*)d_in[6];
  float* out = (float*)d_out;
  char* ws = (char*)d_ws;

  // workspace layout (~113.7 MiB; aliased regions are stream-ordered dead)
  unsigned short* xb    = (unsigned short*)(ws);               // 25165824 (live to k_final)
  unsigned short* wqb   = (unsigned short*)(ws + 25165824);    // 3538944 (dead after kg0)
  unsigned short* qT    = (unsigned short*)(ws + 28704768);    // 25165824 (dead after k_qk)
  unsigned short* yp    = qT;                                  //   alias (kg1->final)
  unsigned short* kT    = (unsigned short*)(ws + 53870592);    // 25165824 (dead after k_qk)
  unsigned short* B_all = kT;                                  //   alias (prep->kg1)
  unsigned short* vP    = (unsigned short*)(ws + 79036416);    // 25165824 (kg0->kg1)
  float* ns             = (float*)(ws + 104202240);            // 98304 (k_qk atomics -> prep)
  float* PA             = (float*)(ws + 104300544);            // 9437184 (k_qk -> prep)

  hipMemsetAsync(ns, 0, 98304, stream);
  k_cvt2<<<dim3(2304), dim3(256), 0, stream>>>(x, xb, 16384 * 768 / 4,
                                               wqkv, wqb, 2304 * 768 / 4);
  kg0_qkv<<<dim3(1536), dim3(512), 0, stream>>>(xb, wqb, qT, kT, vP);
  k_qk<<<dim3(256), dim3(256), 0, stream>>>(qT, kT, PA, ns);
  k_prep<<<dim3(512), dim3(256), 0, stream>>>(PA, ns, temp, wproj, B_all);
  kg1_proj<<<dim3(512), dim3(512), 0, stream>>>(vP, B_all, yp);
  k_final<<<dim3(4096), dim3(256), 0, stream>>>(yp, xb, cw, gamma, beta, out);
}

// Round 14
// 201.007 us; speedup vs baseline: 1.1874x; 1.0122x over previous
//
#include <hip/hip_runtime.h>

#define DEVI __device__ __forceinline__

typedef __bf16 bf16x8 __attribute__((ext_vector_type(8)));
typedef float f32x4 __attribute__((ext_vector_type(4)));

// ---------- small helpers ----------
DEVI unsigned short f2bf(float f) {
  unsigned u = __builtin_bit_cast(unsigned, f);
  u += 0x7FFFu + ((u >> 16) & 1u);   // RNE
  return (unsigned short)(u >> 16);
}
DEVI float bf2f(unsigned short s) {
  return __builtin_bit_cast(float, ((unsigned)s) << 16);
}
DEVI f32x4 mfma16(bf16x8 a, bf16x8 b, f32x4 c) {
  return __builtin_amdgcn_mfma_f32_16x16x32_bf16(a, b, c, 0, 0, 0);
}
DEVI void gload16(const void* g, void* l) {
  __builtin_amdgcn_global_load_lds(
      (const __attribute__((address_space(1))) void*)g,
      (__attribute__((address_space(3))) void*)l, 16, 0, 0);
}
// LDS fragment read, rows ROWB bytes, XOR-swizzle byte ^= (row&7)<<4
template <int ROWB>
DEVI bf16x8 frag_ld(const char* lds, int row, int kb) {
  int off = row * ROWB + (kb ^ ((row & 7) << 4));
  return __builtin_bit_cast(bf16x8, *(const uint4*)(lds + off));
}
DEVI float ssq8(uint4 u) {
  unsigned a[4] = {u.x, u.y, u.z, u.w};
  float s = 0.f;
#pragma unroll
  for (int i = 0; i < 4; ++i) {
    float lo = __builtin_bit_cast(float, a[i] << 16);
    float hi = __builtin_bit_cast(float, a[i] & 0xFFFF0000u);
    s += lo * lo + hi * hi;
  }
  return s;
}
DEVI float ssqbf8(bf16x8 v) { return ssq8(__builtin_bit_cast(uint4, v)); }

// ---------- fp32 -> bf16 convert (+ ns zeroing in block 2304) ----------
__global__ __launch_bounds__(256) void k_cvt2(const float* __restrict__ a,
                                              unsigned short* __restrict__ oa, int n4a,
                                              const float* __restrict__ b,
                                              unsigned short* __restrict__ ob, int n4b,
                                              float* __restrict__ ns) {
  const int tid = threadIdx.x;
  if (blockIdx.x < 2048) {
    const int chunk = (blockIdx.x & 7) * 256 + (blockIdx.x >> 3);  // bijective [0,2048)
    const int i0 = chunk * 1536;                                   // 1536 float4 = 8 rows
    for (int i = i0 + tid; i < i0 + 1536; i += 256) {
      float4 f = ((const float4*)a)[i];
      ushort4 o;
      o.x = f2bf(f.x); o.y = f2bf(f.y); o.z = f2bf(f.z); o.w = f2bf(f.w);
      ((ushort4*)oa)[i] = o;
    }
  } else if (blockIdx.x < 2304) {
    for (int i = (blockIdx.x - 2048) * 256 + tid; i < n4b; i += 256 * 256) {
      float4 f = ((const float4*)b)[i];
      ushort4 o;
      o.x = f2bf(f.x); o.y = f2bf(f.y); o.z = f2bf(f.z); o.w = f2bf(f.w);
      ((ushort4*)ob)[i] = o;
    }
  } else {
    float4 z = {0.f, 0.f, 0.f, 0.f};
    for (int i = tid; i < 6144; i += 256) ((float4*)ns)[i] = z;  // 24576 floats
  }
}

// ---------- pipelined 128x192 GEMM body (BK=64, 8 waves 2Mx4N, 2 blocks/CU) ----------
// MODE 0: qkv = x@wqkv^T, grid 1536 (128mt x 12jt = 3 rounds); q/k scatter packed,
//         v via LDS-transpose coalesced rows.
// MODE 1: yp  = vP@B_b^T, grid 512, LDS-transposed coalesced bf16 -> yp
template <int MODE>
DEVI void gemm_body(char* lds, const unsigned short* __restrict__ A,
                    const unsigned short* __restrict__ B0,
                    unsigned short* __restrict__ o0, unsigned short* __restrict__ o1,
                    unsigned short* __restrict__ o2) {
  const int tid = threadIdx.x, l = tid & 63, wid = tid >> 6;
  const int wr = wid >> 2, wc = wid & 3;
  const int xg = blockIdx.x;
  const int CPX = MODE ? 64 : 192;
  const int NJT = MODE ? 4 : 12;
  const int li = (xg & 7) * CPX + (xg >> 3);
  const int jt = li % NJT, mt = li / NJT;
  const int m0 = mt * 128, j0 = jt * 192;
  const unsigned short* Bb = MODE ? B0 + (size_t)(m0 >> 10) * 589824 : B0;

  const unsigned short* srcg[4][2];
  int ldso[4][2];
#pragma unroll
  for (int sg = 0; sg < 4; ++sg) {
    const bool isA = (sg == 0) || (sg == 3);
#pragma unroll
    for (int i = 0; i < 2; ++i) {
      int c;
      if (sg == 0)      c = (wid < 4) ? wid : wid + 4;
      else if (sg == 3) c = (wid < 4) ? wid + 4 : wid + 8;
      else if (sg == 1) { int cc = 2 * wid + i; c = (cc >> 2) * 6 + (cc & 3); }
      else              c = (wid >> 1) * 6 + 4 + (wid & 1);
      const int r0 = 8 * c;
      const int r = r0 + (l >> 3);
      const int scol = ((l & 7) ^ (l >> 3)) << 3;
      srcg[sg][i] = (isA ? A + (size_t)(m0 + r) * 768 : Bb + (size_t)(j0 + r) * 768) + scol;
      ldso[sg][i] = (isA ? 0 : 16384) + r0 * 128;
    }
  }
  const int swz = (l & 7) << 4;
  const int uu = (l >> 4) << 4;
  const int c0 = uu ^ swz;
  const int c1 = (64 | uu) ^ swz;
  const int arow = (wr * 64 + (l & 15)) * 128;
  const int brow = 16384 + (wc * 48 + (l & 15)) * 128;

  f32x4 acc[4][3];
#pragma unroll
  for (int i = 0; i < 4; ++i)
#pragma unroll
    for (int j = 0; j < 3; ++j)
#pragma unroll
      for (int e = 0; e < 4; ++e) acc[i][j][e] = 0.f;
  bf16x8 a[2][2], a2[2][2], b01[2][2], b2[2];

#define STAGE1(sg, nxt, ko) \
  gload16(srcg[sg][0] + (ko), lds + (nxt)*40960 + ldso[sg][0])
#define STAGE2(sg, nxt, ko)                                        \
  do {                                                             \
    gload16(srcg[sg][0] + (ko), lds + (nxt)*40960 + ldso[sg][0]);  \
    gload16(srcg[sg][1] + (ko), lds + (nxt)*40960 + ldso[sg][1]);  \
  } while (0)
#define LD128(off) __builtin_bit_cast(bf16x8, *(const uint4*)(cb_ + (off)))

  STAGE1(0, 0, 0); STAGE2(1, 0, 0); STAGE1(2, 0, 0); STAGE1(3, 0, 0);
  asm volatile("s_waitcnt vmcnt(2)" ::: "memory");
  __builtin_amdgcn_s_barrier();

#define KBODY(KT, LASTF)                                                              \
  {                                                                                   \
    const char* cb_ = lds + ((KT) & 1) * 40960;                                       \
    const int nxt = (((KT) & 1) ^ 1);                                                 \
    const int ko = ((KT) + 1) * 64;                                                   \
    _Pragma("unroll") for (int mf = 0; mf < 2; ++mf) {                                \
      a[mf][0] = LD128(arow + mf * 2048 + c0);                                        \
      a[mf][1] = LD128(arow + mf * 2048 + c1);                                        \
    }                                                                                 \
    _Pragma("unroll") for (int nf = 0; nf < 2; ++nf) {                                \
      b01[nf][0] = LD128(brow + nf * 2048 + c0);                                      \
      b01[nf][1] = LD128(brow + nf * 2048 + c1);                                      \
    }                                                                                 \
    if (!(LASTF)) {                                                                   \
      STAGE1(0, nxt, ko); STAGE2(1, nxt, ko);                                         \
      asm volatile("s_waitcnt vmcnt(3)" ::: "memory");                                \
    } else {                                                                          \
      asm volatile("s_waitcnt vmcnt(0)" ::: "memory");                                \
    }                                                                                 \
    __builtin_amdgcn_s_barrier();                                                     \
    __builtin_amdgcn_s_setprio(1);                                                    \
    _Pragma("unroll") for (int mf = 0; mf < 2; ++mf)                                  \
      _Pragma("unroll") for (int nf = 0; nf < 2; ++nf) {                              \
        acc[mf][nf] = mfma16(a[mf][0], b01[nf][0], acc[mf][nf]);                      \
        acc[mf][nf] = mfma16(a[mf][1], b01[nf][1], acc[mf][nf]);                      \
      }                                                                               \
    __builtin_amdgcn_s_setprio(0);                                                    \
    b2[0] = LD128(brow + 2 * 2048 + c0);                                              \
    b2[1] = LD128(brow + 2 * 2048 + c1);                                              \
    _Pragma("unroll") for (int mf = 0; mf < 2; ++mf) {                                \
      a2[mf][0] = LD128(arow + (mf + 2) * 2048 + c0);                                 \
      a2[mf][1] = LD128(arow + (mf + 2) * 2048 + c1);                                 \
    }                                                                                 \
    if (!(LASTF)) {                                                                   \
      STAGE1(2, nxt, ko); STAGE1(3, nxt, ko);                                        \
      asm volatile("s_waitcnt vmcnt(2)" ::: "memory");                                \
    }                                                                                 \
    __builtin_amdgcn_s_barrier();                                                     \
    __builtin_amdgcn_s_setprio(1);                                                    \
    _Pragma("unroll") for (int mf = 0; mf < 2; ++mf) {                                \
      acc[mf][2] = mfma16(a[mf][0], b2[0], acc[mf][2]);                               \
      acc[mf][2] = mfma16(a[mf][1], b2[1], acc[mf][2]);                               \
    }                                                                                 \
    _Pragma("unroll") for (int mf = 0; mf < 2; ++mf)                                  \
      _Pragma("unroll") for (int nf = 0; nf < 2; ++nf) {                              \
        acc[mf + 2][nf] = mfma16(a2[mf][0], b01[nf][0], acc[mf + 2][nf]);             \
        acc[mf + 2][nf] = mfma16(a2[mf][1], b01[nf][1], acc[mf + 2][nf]);             \
      }                                                                               \
    _Pragma("unroll") for (int mf = 0; mf < 2; ++mf) {                                \
      acc[mf + 2][2] = mfma16(a2[mf][0], b2[0], acc[mf + 2][2]);                      \
      acc[mf + 2][2] = mfma16(a2[mf][1], b2[1], acc[mf + 2][2]);                      \
    }                                                                                 \
    __builtin_amdgcn_s_setprio(0);                                                    \
  }

#pragma unroll 1
  for (int kt = 0; kt < 11; ++kt) KBODY(kt, false);
  KBODY(11, true);
#undef KBODY
#undef STAGE2
#undef STAGE1
#undef LD128

  const int s = MODE ? 3 : (j0 / 768);
  if (MODE == 0 && s < 2) {
    // q/k scatter: packed ushort4 along n into transposed [bh][d][1024]
    const int jin0 = (j0 % 768) + wc * 48 + (l & 15);
    const int ntok0 = m0 + wr * 64 + ((l >> 4) << 2);
    const int bb = m0 >> 10;
#pragma unroll
    for (int mf = 0; mf < 4; ++mf) {
      const int nt = ntok0 + mf * 16;
      const int nin = nt & 1023;
#pragma unroll
      for (int nf = 0; nf < 3; ++nf) {
        const int jj = jin0 + nf * 16;
        const int hh = jj / 96, dd = jj % 96;
        unsigned short* base = (s == 0) ? o0 : o1;
        ushort4 pk;
        pk.x = f2bf(acc[mf][nf][0]); pk.y = f2bf(acc[mf][nf][1]);
        pk.z = f2bf(acc[mf][nf][2]); pk.w = f2bf(acc[mf][nf][3]);
        *(ushort4*)(base + ((size_t)((bb * 8 + hh) * 96 + dd)) * 1024 + nin) = pk;
      }
    }
  } else {
    // v-section (MODE 0, s==2) or MODE 1: LDS-transpose -> coalesced 384B rows.
    // Safe: no ds_reads after the final barrier in KBODY(11,...).
    unsigned short* dst = MODE ? o0 : o2;
    const int colb = MODE ? j0 : (j0 - 1536);
    unsigned short* t = (unsigned short*)lds;   // [128][200]
    const int nl0 = wr * 64 + ((l >> 4) << 2);
    const int cl0 = wc * 48 + (l & 15);
#pragma unroll
    for (int mf = 0; mf < 4; ++mf)
#pragma unroll
      for (int nf = 0; nf < 3; ++nf)
#pragma unroll
        for (int rr = 0; rr < 4; ++rr)
          t[(nl0 + mf * 16 + rr) * 200 + cl0 + nf * 16] = f2bf(acc[mf][nf][rr]);
    __builtin_amdgcn_s_barrier();
    for (int i2 = tid; i2 < 3072; i2 += 512) {
      int r = i2 / 24, ch = i2 % 24;
      uint4 u = *(const uint4*)(t + r * 200 + ch * 8);
      *(uint4*)(dst + (size_t)(m0 + r) * 768 + colb + ch * 8) = u;
    }
  }
}

__global__ __launch_bounds__(512, 4) void kg0_qkv(const unsigned short* __restrict__ A,
                                                  const unsigned short* __restrict__ B0,
                                                  unsigned short* __restrict__ o0,
                                                  unsigned short* __restrict__ o1,
                                                  unsigned short* __restrict__ o2) {
  __shared__ alignas(16) char lds[81920];
  gemm_body<0>(lds, A, B0, o0, o1, o2);
}
__global__ __launch_bounds__(512, 4) void kg1_proj(const unsigned short* __restrict__ A,
                                                   const unsigned short* __restrict__ B0,
                                                   unsigned short* __restrict__ o0) {
  __shared__ alignas(16) char lds[81920];
  gemm_body<1>(lds, A, B0, o0, nullptr, nullptr);
}

// ---------- k_qk: partial A' = q^T k over a K-half -> PA fp32; + ssq atomics ----------
__global__ __launch_bounds__(256) void k_qk(const unsigned short* __restrict__ qT,
                                            const unsigned short* __restrict__ kT,
                                            float* __restrict__ PA,
                                            float* __restrict__ ns) {
  __shared__ alignas(16) char lQK[2][24576];   // per buf: q [96][64] @0, k @12288
  const int blk = blockIdx.x, tid = threadIdx.x, lane = tid & 63, wid = tid >> 6;
  const int bh = blk >> 1, kh = blk & 1;
  const int wr = wid >> 1, wc = wid & 1;
  const unsigned short* qb = qT + (size_t)bh * 96 * 1024 + kh * 512;
  const unsigned short* kb = kT + (size_t)bh * 96 * 1024 + kh * 512;

  const unsigned short* srcp[6];
  int dsto[6];
#pragma unroll
  for (int i = 0; i < 6; ++i) {
    int cid = wid * 6 + i;          // 24 chunks: 12 q + 12 k
    bool isK = cid >= 12;
    int c = isK ? cid - 12 : cid;
    int p = c * 1024 + lane * 16;
    int r = p >> 7, cb = p & 127;
    int cbs = cb ^ ((r & 7) << 4);
    srcp[i] = (isK ? kb : qb) + (size_t)r * 1024 + (cbs >> 1);
    dsto[i] = (isK ? 12288 : 0) + c * 1024;
  }

  f32x4 acc[3][3];
#pragma unroll
  for (int i = 0; i < 3; ++i)
#pragma unroll
    for (int j = 0; j < 3; ++j)
#pragma unroll
      for (int e = 0; e < 4; ++e) acc[i][j][e] = 0.f;
  float sq[3] = {0.f, 0.f, 0.f}, sk[3] = {0.f, 0.f, 0.f};

#pragma unroll
  for (int i = 0; i < 6; ++i) gload16(srcp[i], lQK[0] + dsto[i]);
  asm volatile("s_waitcnt vmcnt(0)" ::: "memory");
  __builtin_amdgcn_s_barrier();

#pragma unroll 1
  for (int kt = 0; kt < 8; ++kt) {
    const char* bq = lQK[kt & 1];
    if (kt < 7) {
      char* nb = lQK[(kt + 1) & 1];
      const int ko = (kt + 1) * 64;
#pragma unroll
      for (int i = 0; i < 6; ++i) gload16(srcp[i] + ko, nb + dsto[i]);
    }
#pragma unroll
    for (int ks = 0; ks < 2; ++ks) {
      const int kb2 = ks * 64 + ((lane >> 4) << 4);
      bf16x8 af[3], bfv[3];
#pragma unroll
      for (int mb = 0; mb < 3; ++mb) af[mb] = frag_ld<128>(bq, wr * 48 + mb * 16 + (lane & 15), kb2);
#pragma unroll
      for (int nb2 = 0; nb2 < 3; ++nb2) bfv[nb2] = frag_ld<128>(bq + 12288, wc * 48 + nb2 * 16 + (lane & 15), kb2);
      if (wc == 0) {
#pragma unroll
        for (int mb = 0; mb < 3; ++mb) sq[mb] += ssqbf8(af[mb]);
      }
      if (wr == 0) {
#pragma unroll
        for (int nb2 = 0; nb2 < 3; ++nb2) sk[nb2] += ssqbf8(bfv[nb2]);
      }
#pragma unroll
      for (int mb = 0; mb < 3; ++mb)
#pragma unroll
        for (int nb2 = 0; nb2 < 3; ++nb2) acc[mb][nb2] = mfma16(af[mb], bfv[nb2], acc[mb][nb2]);
    }
    asm volatile("s_waitcnt vmcnt(0)" ::: "memory");
    __builtin_amdgcn_s_barrier();
  }

  float* pa = PA + (size_t)(bh * 2 + kh) * 9216;
  const int rb = wr * 48 + ((lane >> 4) << 2);
  const int eb = wc * 48 + (lane & 15);
#pragma unroll
  for (int mb = 0; mb < 3; ++mb)
#pragma unroll
    for (int nb = 0; nb < 3; ++nb)
#pragma unroll
      for (int rr = 0; rr < 4; ++rr)
        pa[(rb + mb * 16 + rr) * 96 + eb + nb * 16] = acc[mb][nb][rr];

  if (wc == 0) {
#pragma unroll
    for (int mb = 0; mb < 3; ++mb) {
      float s = sq[mb];
      s += __shfl_xor(s, 16, 64);
      s += __shfl_xor(s, 32, 64);
      if ((lane >> 4) == 0)
        atomicAdd(&ns[bh * 96 + wr * 48 + mb * 16 + (lane & 15)], s);
    }
  }
  if (wr == 0) {
#pragma unroll
    for (int nb2 = 0; nb2 < 3; ++nb2) {
      float s = sk[nb2];
      s += __shfl_xor(s, 16, 64);
      s += __shfl_xor(s, 32, 64);
      if ((lane >> 4) == 0)
        atomicAdd(&ns[12288 + bh * 96 + wc * 48 + nb2 * 16 + (lane & 15)], s);
    }
  }
}

// ---------- fused softmax + B-prep: B_h = softmax(A'_h)^T @ W_h^T ----------
__global__ __launch_bounds__(256) void k_prep(const float* __restrict__ PA,
                                              const float* __restrict__ ns,
                                              const float* __restrict__ temp,
                                              const float* __restrict__ wproj,
                                              unsigned short* __restrict__ B_all) {
  __shared__ alignas(16) char pl[19968 + 39936];   // lPt [96][104] | scratch (aa / lW)
  unsigned short* lPt = (unsigned short*)pl;
  float* aa = (float*)(pl + 19968);                // [96][96] fp32
  unsigned short* lW = (unsigned short*)(pl + 19968);  // [192][104] bf16
  unsigned short* tr = lW;                         // aliased after MFMA ([192][100])
  __shared__ float lrq[96], lrk[96];
  const int blk = blockIdx.x;
  const int idx = blk >> 3;
  const int b = (blk & 7) * 2 + (idx >> 5);
  const int h = (idx >> 2) & 7, cq = idx & 3;
  const int bh = b * 8 + h;
  const int tid = threadIdx.x, l = tid & 63, wid = tid >> 6;
  const int wr = wid >> 1, wc = wid & 1;
  const float invt = 1.f / temp[h];

  if (tid < 96)       lrq[tid] = 1.f / fmaxf(sqrtf(ns[bh * 96 + tid]), 1e-12f);
  else if (tid < 192) lrk[tid - 96] = 1.f / fmaxf(sqrtf(ns[12288 + bh * 96 + tid - 96]), 1e-12f);

  const float4* pp = (const float4*)(PA + (size_t)bh * 2 * 9216);
  for (int i = tid; i < 2304; i += 256) {
    float4 x0 = pp[i], x1 = pp[i + 2304];
    float4 r;
    r.x = x0.x + x1.x; r.y = x0.y + x1.y; r.z = x0.z + x1.z; r.w = x0.w + x1.w;
    ((float4*)aa)[i] = r;
  }
  __syncthreads();

  for (int d = wid; d < 96; d += 4) {
    float v0 = aa[d * 96 + l] * lrq[d] * lrk[l] * invt;
    float v1 = (l < 32) ? aa[d * 96 + 64 + l] * lrq[d] * lrk[64 + l] * invt : -3.0e38f;
    float mx = fmaxf(v0, v1);
#pragma unroll
    for (int off = 32; off; off >>= 1) mx = fmaxf(mx, __shfl_xor(mx, off, 64));
    float p0 = __expf(v0 - mx);
    float p1 = (l < 32) ? __expf(v1 - mx) : 0.f;
    float ssum = p0 + p1;
#pragma unroll
    for (int off = 32; off; off >>= 1) ssum += __shfl_xor(ssum, off, 64);
    float rs = 1.f / ssum;
    lPt[l * 104 + d] = f2bf(p0 * rs);                 // lPt[e][d]
    if (l < 32) lPt[(64 + l) * 104 + d] = f2bf(p1 * rs);
  }
  __syncthreads();                 // aa dead; lW may overwrite scratch

  for (int i2 = tid; i2 < 4608; i2 += 256) {
    int r = i2 / 24, ch = i2 % 24;
    float4 f = *(const float4*)(wproj + (size_t)(cq * 192 + r) * 768 + h * 96 + ch * 4);
    ushort4 o;
    o.x = f2bf(f.x); o.y = f2bf(f.y); o.z = f2bf(f.z); o.w = f2bf(f.w);
    *(ushort4*)(lW + r * 104 + ch * 4) = o;
  }
  __syncthreads();

  f32x4 acc[3][6];
#pragma unroll
  for (int i = 0; i < 3; ++i)
#pragma unroll
    for (int j = 0; j < 6; ++j)
#pragma unroll
      for (int e = 0; e < 4; ++e) acc[i][j][e] = 0.f;

#pragma unroll
  for (int ks = 0; ks < 3; ++ks) {
    const int kof = ks * 32 + ((l >> 4) << 3);
    bf16x8 af[3], bv[6];
#pragma unroll
    for (int mb = 0; mb < 3; ++mb)
      af[mb] = __builtin_bit_cast(bf16x8, *(const uint4*)(lPt + (wr * 48 + mb * 16 + (l & 15)) * 104 + kof));
#pragma unroll
    for (int nb = 0; nb < 6; ++nb)
      bv[nb] = __builtin_bit_cast(bf16x8, *(const uint4*)(lW + (wc * 96 + nb * 16 + (l & 15)) * 104 + kof));
#pragma unroll
    for (int mb = 0; mb < 3; ++mb)
#pragma unroll
      for (int nb = 0; nb < 6; ++nb) acc[mb][nb] = mfma16(af[mb], bv[nb], acc[mb][nb]);
  }

  __syncthreads();                 // all lW reads done; safe to alias as tr
  const int e0 = wr * 48 + ((l >> 4) << 2);
  const int cl0 = wc * 96 + (l & 15);
#pragma unroll
  for (int mb = 0; mb < 3; ++mb)
#pragma unroll
    for (int nb = 0; nb < 6; ++nb) {
      ushort4 pk;
      pk.x = f2bf(acc[mb][nb][0]); pk.y = f2bf(acc[mb][nb][1]);
      pk.z = f2bf(acc[mb][nb][2]); pk.w = f2bf(acc[mb][nb][3]);
      *(ushort4*)(tr + (cl0 + nb * 16) * 100 + e0 + mb * 16) = pk;
    }
  __syncthreads();
  for (int i2 = tid; i2 < 2304; i2 += 256) {
    int r = i2 / 12, ch = i2 % 12;
    uint4 u = *(const uint4*)(tr + r * 100 + ch * 8);
    *(uint4*)(B_all + ((size_t)(b * 768) + cq * 192 + r) * 768 + h * 96 + ch * 8) = u;
  }
}

// ---------- final: y = yp(bf16) + 0.1*dwconv3x3(xb bf16); LayerNorm ----------
__global__ __launch_bounds__(256) void k_final(const unsigned short* __restrict__ yp,
                                               const unsigned short* __restrict__ xb16,
                                               const float* __restrict__ cw,
                                               const float* __restrict__ gamma,
                                               const float* __restrict__ beta,
                                               float* __restrict__ out) {
  const int wid = threadIdx.x >> 6, lane = threadIdx.x & 63;
  const int m = (blockIdx.x & 7) * 2048 + (blockIdx.x >> 3) * 4 + wid;  // token id
  const int bb = m >> 10, n = m & 1023, yy = n >> 5, xx = n & 31;
  const unsigned short* xb = xb16 + (size_t)bb * 1024 * 768;

  float yv[3][4];
#pragma unroll
  for (int g = 0; g < 3; ++g) {
    const int c = g * 256 + lane * 4;
    float w36[36];
    const float4* wp = (const float4*)(cw + (size_t)c * 9);
#pragma unroll
    for (int i = 0; i < 9; ++i) *(float4*)(w36 + i * 4) = wp[i];

    float a0 = 0.f, a1 = 0.f, a2 = 0.f, a3 = 0.f;
#pragma unroll
    for (int dy = -1; dy <= 1; ++dy) {
      int ny = yy + dy;
      if ((unsigned)ny < 32u) {
#pragma unroll
        for (int dx = -1; dx <= 1; ++dx) {
          int nx = xx + dx;
          if ((unsigned)nx < 32u) {
            ushort4 v = *(const ushort4*)(xb + (size_t)(ny * 32 + nx) * 768 + c);
            const int j = (dy + 1) * 3 + (dx + 1);
            a0 += w36[0 * 9 + j] * bf2f(v.x);
            a1 += w36[1 * 9 + j] * bf2f(v.y);
            a2 += w36[2 * 9 + j] * bf2f(v.z);
            a3 += w36[3 * 9 + j] * bf2f(v.w);
          }
        }
      }
    }
    ushort4 f = *(const ushort4*)(yp + (size_t)m * 768 + c);
    yv[g][0] = bf2f(f.x) + 0.1f * a0;
    yv[g][1] = bf2f(f.y) + 0.1f * a1;
    yv[g][2] = bf2f(f.z) + 0.1f * a2;
    yv[g][3] = bf2f(f.w) + 0.1f * a3;
  }

  float s1 = 0.f, s2 = 0.f;
#pragma unroll
  for (int g = 0; g < 3; ++g)
#pragma unroll
    for (int e = 0; e < 4; ++e) { s1 += yv[g][e]; s2 += yv[g][e] * yv[g][e]; }
#pragma unroll
  for (int off = 32; off; off >>= 1) {
    s1 += __shfl_xor(s1, off, 64);
    s2 += __shfl_xor(s2, off, 64);
  }
  const float mu = s1 * (1.f / 768.f);
  const float var = s2 * (1.f / 768.f) - mu * mu;
  const float rs = rsqrtf(var + 1e-5f);

#pragma unroll
  for (int g = 0; g < 3; ++g) {
    const int c = g * 256 + lane * 4;
    float4 gm = *(const float4*)(gamma + c);
    float4 bt = *(const float4*)(beta + c);
    float4 o;
    o.x = (yv[g][0] - mu) * rs * gm.x + bt.x;
    o.y = (yv[g][1] - mu) * rs * gm.y + bt.y;
    o.z = (yv[g][2] - mu) * rs * gm.z + bt.z;
    o.w = (yv[g][3] - mu) * rs * gm.w + bt.w;
    *(float4*)(out + (size_t)m * 768 + c) = o;
  }
}

// ---------- host ----------
extern "C" void kernel_launch(void* const* d_in, const int* in_sizes, int n_in,
                              void* d_out, int out_size, void* d_ws, size_t ws_size,
                              hipStream_t stream) {
  const float* x     = (const float*)d_in[0];
  const float* wqkv  = (const float*)d_in[1];
  const float* wproj = (const float*)d_in[2];
  const float* temp  = (const float*)d_in[3];
  const float* cw    = (const float*)d_in[4];
  const float* gamma = (const float*)d_in[5];
  const float* beta  = (const float*)d_in[6];
  float* out = (float*)d_out;
  char* ws = (char*)d_ws;

  // workspace layout (~113.7 MiB; aliased regions are stream-ordered dead)
  unsigned short* xb    = (unsigned short*)(ws);               // 25165824 (live to k_final)
  unsigned short* wqb   = (unsigned short*)(ws + 25165824);    // 3538944 (dead after kg0)
  unsigned short* qT    = (unsigned short*)(ws + 28704768);    // 25165824 (dead after k_qk)
  unsigned short* yp    = qT;                                  //   alias (kg1->final)
  unsigned short* kT    = (unsigned short*)(ws + 53870592);    // 25165824 (dead after k_qk)
  unsigned short* B_all = kT;                                  //   alias (prep->kg1)
  unsigned short* vP    = (unsigned short*)(ws + 79036416);    // 25165824 (kg0->kg1)
  float* ns             = (float*)(ws + 104202240);            // 98304 (k_qk atomics -> prep)
  float* PA             = (float*)(ws + 104300544);            // 9437184 (k_qk -> prep)

  k_cvt2<<<dim3(2305), dim3(256), 0, stream>>>(x, xb, 16384 * 768 / 4,
                                               wqkv, wqb, 2304 * 768 / 4, ns);
  kg0_qkv<<<dim3(1536), dim3(512), 0, stream>>>(xb, wqb, qT, kT, vP);
  k_qk<<<dim3(256), dim3(256), 0, stream>>>(qT, kT, PA, ns);
  k_prep<<<dim3(512), dim3(256), 0, stream>>>(PA, ns, temp, wproj, B_all);
  kg1_proj<<<dim3(512), dim3(512), 0, stream>>>(vP, B_all, yp);
  k_final<<<dim3(4096), dim3(256), 0, stream>>>(yp, xb, cw, gamma, beta, out);
}

// Round 15
// 193.873 us; speedup vs baseline: 1.2311x; 1.0368x over previous
//
#include <hip/hip_runtime.h>

#define DEVI __device__ __forceinline__

typedef __bf16 bf16x8 __attribute__((ext_vector_type(8)));
typedef float f32x4 __attribute__((ext_vector_type(4)));

// ---------- small helpers ----------
DEVI unsigned short f2bf(float f) {
  unsigned u = __builtin_bit_cast(unsigned, f);
  u += 0x7FFFu + ((u >> 16) & 1u);   // RNE
  return (unsigned short)(u >> 16);
}
DEVI float bf2f(unsigned short s) {
  return __builtin_bit_cast(float, ((unsigned)s) << 16);
}
DEVI f32x4 mfma16(bf16x8 a, bf16x8 b, f32x4 c) {
  return __builtin_amdgcn_mfma_f32_16x16x32_bf16(a, b, c, 0, 0, 0);
}
DEVI void gload16(const void* g, void* l) {
  __builtin_amdgcn_global_load_lds(
      (const __attribute__((address_space(1))) void*)g,
      (__attribute__((address_space(3))) void*)l, 16, 0, 0);
}
// LDS fragment read, rows ROWB bytes, XOR-swizzle byte ^= (row&7)<<4
template <int ROWB>
DEVI bf16x8 frag_ld(const char* lds, int row, int kb) {
  int off = row * ROWB + (kb ^ ((row & 7) << 4));
  return __builtin_bit_cast(bf16x8, *(const uint4*)(lds + off));
}
DEVI float ssq8(uint4 u) {
  unsigned a[4] = {u.x, u.y, u.z, u.w};
  float s = 0.f;
#pragma unroll
  for (int i = 0; i < 4; ++i) {
    float lo = __builtin_bit_cast(float, a[i] << 16);
    float hi = __builtin_bit_cast(float, a[i] & 0xFFFF0000u);
    s += lo * lo + hi * hi;
  }
  return s;
}
DEVI float ssqbf8(bf16x8 v) { return ssq8(__builtin_bit_cast(uint4, v)); }

// ---------- fp32 -> bf16 convert (+ ns zeroing in block 2304) ----------
__global__ __launch_bounds__(256) void k_cvt2(const float* __restrict__ a,
                                              unsigned short* __restrict__ oa, int n4a,
                                              const float* __restrict__ b,
                                              unsigned short* __restrict__ ob, int n4b,
                                              float* __restrict__ ns) {
  const int tid = threadIdx.x;
  if (blockIdx.x < 2048) {
    const int chunk = (blockIdx.x & 7) * 256 + (blockIdx.x >> 3);  // bijective [0,2048)
    const int i0 = chunk * 1536;                                   // 1536 float4 = 8 rows
    for (int i = i0 + tid; i < i0 + 1536; i += 256) {
      float4 f = ((const float4*)a)[i];
      ushort4 o;
      o.x = f2bf(f.x); o.y = f2bf(f.y); o.z = f2bf(f.z); o.w = f2bf(f.w);
      ((ushort4*)oa)[i] = o;
    }
  } else if (blockIdx.x < 2304) {
    for (int i = (blockIdx.x - 2048) * 256 + tid; i < n4b; i += 256 * 256) {
      float4 f = ((const float4*)b)[i];
      ushort4 o;
      o.x = f2bf(f.x); o.y = f2bf(f.y); o.z = f2bf(f.z); o.w = f2bf(f.w);
      ((ushort4*)ob)[i] = o;
    }
  } else {
    float4 z = {0.f, 0.f, 0.f, 0.f};
    for (int i = tid; i < 6144; i += 256) ((float4*)ns)[i] = z;  // 24576 floats
  }
}

// ---------- pipelined 128x192 GEMM body (BK=64, 8 waves 2Mx4N, 2 blocks/CU) ----------
// MODE 0: qkv = x@wqkv^T, grid 1536 (128mt x 12jt = 3 rounds); ALL outputs via
//         LDS-transpose, fully coalesced rows (q/k: 256B rows; v: 384B rows).
// MODE 1: yp  = vP@B_b^T, grid 512, LDS-transposed coalesced bf16 -> yp
template <int MODE>
DEVI void gemm_body(char* lds, const unsigned short* __restrict__ A,
                    const unsigned short* __restrict__ B0,
                    unsigned short* __restrict__ o0, unsigned short* __restrict__ o1,
                    unsigned short* __restrict__ o2) {
  const int tid = threadIdx.x, l = tid & 63, wid = tid >> 6;
  const int wr = wid >> 2, wc = wid & 3;
  const int xg = blockIdx.x;
  const int CPX = MODE ? 64 : 192;
  const int NJT = MODE ? 4 : 12;
  const int li = (xg & 7) * CPX + (xg >> 3);
  const int jt = li % NJT, mt = li / NJT;
  const int m0 = mt * 128, j0 = jt * 192;
  const unsigned short* Bb = MODE ? B0 + (size_t)(m0 >> 10) * 589824 : B0;

  const unsigned short* srcg[4][2];
  int ldso[4][2];
#pragma unroll
  for (int sg = 0; sg < 4; ++sg) {
    const bool isA = (sg == 0) || (sg == 3);
#pragma unroll
    for (int i = 0; i < 2; ++i) {
      int c;
      if (sg == 0)      c = (wid < 4) ? wid : wid + 4;
      else if (sg == 3) c = (wid < 4) ? wid + 4 : wid + 8;
      else if (sg == 1) { int cc = 2 * wid + i; c = (cc >> 2) * 6 + (cc & 3); }
      else              c = (wid >> 1) * 6 + 4 + (wid & 1);
      const int r0 = 8 * c;
      const int r = r0 + (l >> 3);
      const int scol = ((l & 7) ^ (l >> 3)) << 3;
      srcg[sg][i] = (isA ? A + (size_t)(m0 + r) * 768 : Bb + (size_t)(j0 + r) * 768) + scol;
      ldso[sg][i] = (isA ? 0 : 16384) + r0 * 128;
    }
  }
  const int swz = (l & 7) << 4;
  const int uu = (l >> 4) << 4;
  const int c0 = uu ^ swz;
  const int c1 = (64 | uu) ^ swz;
  const int arow = (wr * 64 + (l & 15)) * 128;
  const int brow = 16384 + (wc * 48 + (l & 15)) * 128;

  f32x4 acc[4][3];
#pragma unroll
  for (int i = 0; i < 4; ++i)
#pragma unroll
    for (int j = 0; j < 3; ++j)
#pragma unroll
      for (int e = 0; e < 4; ++e) acc[i][j][e] = 0.f;
  bf16x8 a[2][2], a2[2][2], b01[2][2], b2[2];

#define STAGE1(sg, nxt, ko) \
  gload16(srcg[sg][0] + (ko), lds + (nxt)*40960 + ldso[sg][0])
#define STAGE2(sg, nxt, ko)                                        \
  do {                                                             \
    gload16(srcg[sg][0] + (ko), lds + (nxt)*40960 + ldso[sg][0]);  \
    gload16(srcg[sg][1] + (ko), lds + (nxt)*40960 + ldso[sg][1]);  \
  } while (0)
#define LD128(off) __builtin_bit_cast(bf16x8, *(const uint4*)(cb_ + (off)))

  STAGE1(0, 0, 0); STAGE2(1, 0, 0); STAGE1(2, 0, 0); STAGE1(3, 0, 0);
  asm volatile("s_waitcnt vmcnt(2)" ::: "memory");
  __builtin_amdgcn_s_barrier();

#define KBODY(KT, LASTF)                                                              \
  {                                                                                   \
    const char* cb_ = lds + ((KT) & 1) * 40960;                                       \
    const int nxt = (((KT) & 1) ^ 1);                                                 \
    const int ko = ((KT) + 1) * 64;                                                   \
    _Pragma("unroll") for (int mf = 0; mf < 2; ++mf) {                                \
      a[mf][0] = LD128(arow + mf * 2048 + c0);                                        \
      a[mf][1] = LD128(arow + mf * 2048 + c1);                                        \
    }                                                                                 \
    _Pragma("unroll") for (int nf = 0; nf < 2; ++nf) {                                \
      b01[nf][0] = LD128(brow + nf * 2048 + c0);                                      \
      b01[nf][1] = LD128(brow + nf * 2048 + c1);                                      \
    }                                                                                 \
    if (!(LASTF)) {                                                                   \
      STAGE1(0, nxt, ko); STAGE2(1, nxt, ko);                                         \
      asm volatile("s_waitcnt vmcnt(3)" ::: "memory");                                \
    } else {                                                                          \
      asm volatile("s_waitcnt vmcnt(0)" ::: "memory");                                \
    }                                                                                 \
    __builtin_amdgcn_s_barrier();                                                     \
    __builtin_amdgcn_s_setprio(1);                                                    \
    _Pragma("unroll") for (int mf = 0; mf < 2; ++mf)                                  \
      _Pragma("unroll") for (int nf = 0; nf < 2; ++nf) {                              \
        acc[mf][nf] = mfma16(a[mf][0], b01[nf][0], acc[mf][nf]);                      \
        acc[mf][nf] = mfma16(a[mf][1], b01[nf][1], acc[mf][nf]);                      \
      }                                                                               \
    __builtin_amdgcn_s_setprio(0);                                                    \
    b2[0] = LD128(brow + 2 * 2048 + c0);                                              \
    b2[1] = LD128(brow + 2 * 2048 + c1);                                              \
    _Pragma("unroll") for (int mf = 0; mf < 2; ++mf) {                                \
      a2[mf][0] = LD128(arow + (mf + 2) * 2048 + c0);                                 \
      a2[mf][1] = LD128(arow + (mf + 2) * 2048 + c1);                                 \
    }                                                                                 \
    if (!(LASTF)) {                                                                   \
      STAGE1(2, nxt, ko); STAGE1(3, nxt, ko);                                        \
      asm volatile("s_waitcnt vmcnt(2)" ::: "memory");                                \
    }                                                                                 \
    __builtin_amdgcn_s_barrier();                                                     \
    __builtin_amdgcn_s_setprio(1);                                                    \
    _Pragma("unroll") for (int mf = 0; mf < 2; ++mf) {                                \
      acc[mf][2] = mfma16(a[mf][0], b2[0], acc[mf][2]);                               \
      acc[mf][2] = mfma16(a[mf][1], b2[1], acc[mf][2]);                               \
    }                                                                                 \
    _Pragma("unroll") for (int mf = 0; mf < 2; ++mf)                                  \
      _Pragma("unroll") for (int nf = 0; nf < 2; ++nf) {                              \
        acc[mf + 2][nf] = mfma16(a2[mf][0], b01[nf][0], acc[mf + 2][nf]);             \
        acc[mf + 2][nf] = mfma16(a2[mf][1], b01[nf][1], acc[mf + 2][nf]);             \
      }                                                                               \
    _Pragma("unroll") for (int mf = 0; mf < 2; ++mf) {                                \
      acc[mf + 2][2] = mfma16(a2[mf][0], b2[0], acc[mf + 2][2]);                      \
      acc[mf + 2][2] = mfma16(a2[mf][1], b2[1], acc[mf + 2][2]);                      \
    }                                                                                 \
    __builtin_amdgcn_s_setprio(0);                                                    \
  }

#pragma unroll 1
  for (int kt = 0; kt < 11; ++kt) KBODY(kt, false);
  KBODY(11, true);
#undef KBODY
#undef STAGE2
#undef STAGE1
#undef LD128

  const int s = MODE ? 3 : (j0 / 768);
  if (MODE == 0 && s < 2) {
    // q/k: LDS-transpose to [192 j][136 pad], then 256B coalesced rows into
    // transposed [bh][d][1024] layout.
    unsigned short* t = (unsigned short*)lds;
    unsigned short* base = (s == 0) ? o0 : o1;
    const int nl0 = wr * 64 + ((l >> 4) << 2);   // n-local
    const int cl0 = wc * 48 + (l & 15);          // j-local
#pragma unroll
    for (int mf = 0; mf < 4; ++mf)
#pragma unroll
      for (int nf = 0; nf < 3; ++nf)
#pragma unroll
        for (int rr = 0; rr < 4; ++rr)
          t[(cl0 + nf * 16) * 136 + nl0 + mf * 16 + rr] = f2bf(acc[mf][nf][rr]);
    asm volatile("s_waitcnt lgkmcnt(0)" ::: "memory");
    __builtin_amdgcn_s_barrier();
    const int bb = m0 >> 10;
    const int nin = m0 & 1023;
    const int jb = j0 % 768;
    for (int i2 = tid; i2 < 3072; i2 += 512) {   // 192 rows x 16 chunks of 16B
      int r = i2 >> 4, ch = i2 & 15;
      int jj = jb + r;
      int hh = jj / 96, dd = jj % 96;
      uint4 u = *(const uint4*)(t + r * 136 + ch * 8);
      *(uint4*)(base + ((size_t)((bb * 8 + hh) * 96 + dd)) * 1024 + nin + ch * 8) = u;
    }
  } else {
    // v-section (MODE 0, s==2) or MODE 1: LDS-transpose -> coalesced 384B rows.
    unsigned short* dst = MODE ? o0 : o2;
    const int colb = MODE ? j0 : (j0 - 1536);
    unsigned short* t = (unsigned short*)lds;   // [128][200]
    const int nl0 = wr * 64 + ((l >> 4) << 2);
    const int cl0 = wc * 48 + (l & 15);
#pragma unroll
    for (int mf = 0; mf < 4; ++mf)
#pragma unroll
      for (int nf = 0; nf < 3; ++nf)
#pragma unroll
        for (int rr = 0; rr < 4; ++rr)
          t[(nl0 + mf * 16 + rr) * 200 + cl0 + nf * 16] = f2bf(acc[mf][nf][rr]);
    asm volatile("s_waitcnt lgkmcnt(0)" ::: "memory");
    __builtin_amdgcn_s_barrier();
    for (int i2 = tid; i2 < 3072; i2 += 512) {
      int r = i2 / 24, ch = i2 % 24;
      uint4 u = *(const uint4*)(t + r * 200 + ch * 8);
      *(uint4*)(dst + (size_t)(m0 + r) * 768 + colb + ch * 8) = u;
    }
  }
}

__global__ __launch_bounds__(512, 4) void kg0_qkv(const unsigned short* __restrict__ A,
                                                  const unsigned short* __restrict__ B0,
                                                  unsigned short* __restrict__ o0,
                                                  unsigned short* __restrict__ o1,
                                                  unsigned short* __restrict__ o2) {
  __shared__ alignas(16) char lds[81920];
  gemm_body<0>(lds, A, B0, o0, o1, o2);
}
__global__ __launch_bounds__(512, 4) void kg1_proj(const unsigned short* __restrict__ A,
                                                   const unsigned short* __restrict__ B0,
                                                   unsigned short* __restrict__ o0) {
  __shared__ alignas(16) char lds[81920];
  gemm_body<1>(lds, A, B0, o0, nullptr, nullptr);
}

// ---------- k_qk: partial A' = q^T k over a K-half -> PA fp32; + ssq atomics ----------
__global__ __launch_bounds__(256) void k_qk(const unsigned short* __restrict__ qT,
                                            const unsigned short* __restrict__ kT,
                                            float* __restrict__ PA,
                                            float* __restrict__ ns) {
  __shared__ alignas(16) char lQK[2][24576];   // per buf: q [96][64] @0, k @12288
  const int blk = blockIdx.x, tid = threadIdx.x, lane = tid & 63, wid = tid >> 6;
  const int bh = blk >> 1, kh = blk & 1;
  const int wr = wid >> 1, wc = wid & 1;
  const unsigned short* qb = qT + (size_t)bh * 96 * 1024 + kh * 512;
  const unsigned short* kb = kT + (size_t)bh * 96 * 1024 + kh * 512;

  const unsigned short* srcp[6];
  int dsto[6];
#pragma unroll
  for (int i = 0; i < 6; ++i) {
    int cid = wid * 6 + i;          // 24 chunks: 12 q + 12 k
    bool isK = cid >= 12;
    int c = isK ? cid - 12 : cid;
    int p = c * 1024 + lane * 16;
    int r = p >> 7, cb = p & 127;
    int cbs = cb ^ ((r & 7) << 4);
    srcp[i] = (isK ? kb : qb) + (size_t)r * 1024 + (cbs >> 1);
    dsto[i] = (isK ? 12288 : 0) + c * 1024;
  }

  f32x4 acc[3][3];
#pragma unroll
  for (int i = 0; i < 3; ++i)
#pragma unroll
    for (int j = 0; j < 3; ++j)
#pragma unroll
      for (int e = 0; e < 4; ++e) acc[i][j][e] = 0.f;
  float sq[3] = {0.f, 0.f, 0.f}, sk[3] = {0.f, 0.f, 0.f};

#pragma unroll
  for (int i = 0; i < 6; ++i) gload16(srcp[i], lQK[0] + dsto[i]);
  asm volatile("s_waitcnt vmcnt(0)" ::: "memory");
  __builtin_amdgcn_s_barrier();

#pragma unroll 1
  for (int kt = 0; kt < 8; ++kt) {
    const char* bq = lQK[kt & 1];
    if (kt < 7) {
      char* nb = lQK[(kt + 1) & 1];
      const int ko = (kt + 1) * 64;
#pragma unroll
      for (int i = 0; i < 6; ++i) gload16(srcp[i] + ko, nb + dsto[i]);
    }
#pragma unroll
    for (int ks = 0; ks < 2; ++ks) {
      const int kb2 = ks * 64 + ((lane >> 4) << 4);
      bf16x8 af[3], bfv[3];
#pragma unroll
      for (int mb = 0; mb < 3; ++mb) af[mb] = frag_ld<128>(bq, wr * 48 + mb * 16 + (lane & 15), kb2);
#pragma unroll
      for (int nb2 = 0; nb2 < 3; ++nb2) bfv[nb2] = frag_ld<128>(bq + 12288, wc * 48 + nb2 * 16 + (lane & 15), kb2);
      if (wc == 0) {
#pragma unroll
        for (int mb = 0; mb < 3; ++mb) sq[mb] += ssqbf8(af[mb]);
      }
      if (wr == 0) {
#pragma unroll
        for (int nb2 = 0; nb2 < 3; ++nb2) sk[nb2] += ssqbf8(bfv[nb2]);
      }
#pragma unroll
      for (int mb = 0; mb < 3; ++mb)
#pragma unroll
        for (int nb2 = 0; nb2 < 3; ++nb2) acc[mb][nb2] = mfma16(af[mb], bfv[nb2], acc[mb][nb2]);
    }
    asm volatile("s_waitcnt vmcnt(0)" ::: "memory");
    __builtin_amdgcn_s_barrier();
  }

  float* pa = PA + (size_t)(bh * 2 + kh) * 9216;
  const int rb = wr * 48 + ((lane >> 4) << 2);
  const int eb = wc * 48 + (lane & 15);
#pragma unroll
  for (int mb = 0; mb < 3; ++mb)
#pragma unroll
    for (int nb = 0; nb < 3; ++nb)
#pragma unroll
      for (int rr = 0; rr < 4; ++rr)
        pa[(rb + mb * 16 + rr) * 96 + eb + nb * 16] = acc[mb][nb][rr];

  if (wc == 0) {
#pragma unroll
    for (int mb = 0; mb < 3; ++mb) {
      float s = sq[mb];
      s += __shfl_xor(s, 16, 64);
      s += __shfl_xor(s, 32, 64);
      if ((lane >> 4) == 0)
        atomicAdd(&ns[bh * 96 + wr * 48 + mb * 16 + (lane & 15)], s);
    }
  }
  if (wr == 0) {
#pragma unroll
    for (int nb2 = 0; nb2 < 3; ++nb2) {
      float s = sk[nb2];
      s += __shfl_xor(s, 16, 64);
      s += __shfl_xor(s, 32, 64);
      if ((lane >> 4) == 0)
        atomicAdd(&ns[12288 + bh * 96 + wc * 48 + nb2 * 16 + (lane & 15)], s);
    }
  }
}

// ---------- fused softmax + B-prep: B_h = softmax(A'_h)^T @ W_h^T ----------
__global__ __launch_bounds__(256) void k_prep(const float* __restrict__ PA,
                                              const float* __restrict__ ns,
                                              const float* __restrict__ temp,
                                              const float* __restrict__ wproj,
                                              unsigned short* __restrict__ B_all) {
  __shared__ alignas(16) char pl[19968 + 39936];   // lPt [96][104] | scratch (aa / lW)
  unsigned short* lPt = (unsigned short*)pl;
  float* aa = (float*)(pl + 19968);                // [96][96] fp32
  unsigned short* lW = (unsigned short*)(pl + 19968);  // [192][104] bf16
  unsigned short* tr = lW;                         // aliased after MFMA ([192][100])
  __shared__ float lrq[96], lrk[96];
  const int blk = blockIdx.x;
  const int idx = blk >> 3;
  const int b = (blk & 7) * 2 + (idx >> 5);
  const int h = (idx >> 2) & 7, cq = idx & 3;
  const int bh = b * 8 + h;
  const int tid = threadIdx.x, l = tid & 63, wid = tid >> 6;
  const int wr = wid >> 1, wc = wid & 1;
  const float invt = 1.f / temp[h];

  if (tid < 96)       lrq[tid] = 1.f / fmaxf(sqrtf(ns[bh * 96 + tid]), 1e-12f);
  else if (tid < 192) lrk[tid - 96] = 1.f / fmaxf(sqrtf(ns[12288 + bh * 96 + tid - 96]), 1e-12f);

  const float4* pp = (const float4*)(PA + (size_t)bh * 2 * 9216);
  for (int i = tid; i < 2304; i += 256) {
    float4 x0 = pp[i], x1 = pp[i + 2304];
    float4 r;
    r.x = x0.x + x1.x; r.y = x0.y + x1.y; r.z = x0.z + x1.z; r.w = x0.w + x1.w;
    ((float4*)aa)[i] = r;
  }
  __syncthreads();

  for (int d = wid; d < 96; d += 4) {
    float v0 = aa[d * 96 + l] * lrq[d] * lrk[l] * invt;
    float v1 = (l < 32) ? aa[d * 96 + 64 + l] * lrq[d] * lrk[64 + l] * invt : -3.0e38f;
    float mx = fmaxf(v0, v1);
#pragma unroll
    for (int off = 32; off; off >>= 1) mx = fmaxf(mx, __shfl_xor(mx, off, 64));
    float p0 = __expf(v0 - mx);
    float p1 = (l < 32) ? __expf(v1 - mx) : 0.f;
    float ssum = p0 + p1;
#pragma unroll
    for (int off = 32; off; off >>= 1) ssum += __shfl_xor(ssum, off, 64);
    float rs = 1.f / ssum;
    lPt[l * 104 + d] = f2bf(p0 * rs);                 // lPt[e][d]
    if (l < 32) lPt[(64 + l) * 104 + d] = f2bf(p1 * rs);
  }
  __syncthreads();                 // aa dead; lW may overwrite scratch

  for (int i2 = tid; i2 < 4608; i2 += 256) {
    int r = i2 / 24, ch = i2 % 24;
    float4 f = *(const float4*)(wproj + (size_t)(cq * 192 + r) * 768 + h * 96 + ch * 4);
    ushort4 o;
    o.x = f2bf(f.x); o.y = f2bf(f.y); o.z = f2bf(f.z); o.w = f2bf(f.w);
    *(ushort4*)(lW + r * 104 + ch * 4) = o;
  }
  __syncthreads();

  f32x4 acc[3][6];
#pragma unroll
  for (int i = 0; i < 3; ++i)
#pragma unroll
    for (int j = 0; j < 6; ++j)
#pragma unroll
      for (int e = 0; e < 4; ++e) acc[i][j][e] = 0.f;

#pragma unroll
  for (int ks = 0; ks < 3; ++ks) {
    const int kof = ks * 32 + ((l >> 4) << 3);
    bf16x8 af[3], bv[6];
#pragma unroll
    for (int mb = 0; mb < 3; ++mb)
      af[mb] = __builtin_bit_cast(bf16x8, *(const uint4*)(lPt + (wr * 48 + mb * 16 + (l & 15)) * 104 + kof));
#pragma unroll
    for (int nb = 0; nb < 6; ++nb)
      bv[nb] = __builtin_bit_cast(bf16x8, *(const uint4*)(lW + (wc * 96 + nb * 16 + (l & 15)) * 104 + kof));
#pragma unroll
    for (int mb = 0; mb < 3; ++mb)
#pragma unroll
      for (int nb = 0; nb < 6; ++nb) acc[mb][nb] = mfma16(af[mb], bv[nb], acc[mb][nb]);
  }

  __syncthreads();                 // all lW reads done; safe to alias as tr
  const int e0 = wr * 48 + ((l >> 4) << 2);
  const int cl0 = wc * 96 + (l & 15);
#pragma unroll
  for (int mb = 0; mb < 3; ++mb)
#pragma unroll
    for (int nb = 0; nb < 6; ++nb) {
      ushort4 pk;
      pk.x = f2bf(acc[mb][nb][0]); pk.y = f2bf(acc[mb][nb][1]);
      pk.z = f2bf(acc[mb][nb][2]); pk.w = f2bf(acc[mb][nb][3]);
      *(ushort4*)(tr + (cl0 + nb * 16) * 100 + e0 + mb * 16) = pk;
    }
  __syncthreads();
  for (int i2 = tid; i2 < 2304; i2 += 256) {
    int r = i2 / 12, ch = i2 % 12;
    uint4 u = *(const uint4*)(tr + r * 100 + ch * 8);
    *(uint4*)(B_all + ((size_t)(b * 768) + cq * 192 + r) * 768 + h * 96 + ch * 8) = u;
  }
}

// ---------- final: y = yp(bf16) + 0.1*dwconv3x3(xb bf16); LayerNorm ----------
__global__ __launch_bounds__(256) void k_final(const unsigned short* __restrict__ yp,
                                               const unsigned short* __restrict__ xb16,
                                               const float* __restrict__ cw,
                                               const float* __restrict__ gamma,
                                               const float* __restrict__ beta,
                                               float* __restrict__ out) {
  const int wid = threadIdx.x >> 6, lane = threadIdx.x & 63;
  const int m = (blockIdx.x & 7) * 2048 + (blockIdx.x >> 3) * 4 + wid;  // token id
  const int bb = m >> 10, n = m & 1023, yy = n >> 5, xx = n & 31;
  const unsigned short* xb = xb16 + (size_t)bb * 1024 * 768;

  float yv[3][4];
#pragma unroll
  for (int g = 0; g < 3; ++g) {
    const int c = g * 256 + lane * 4;
    float w36[36];
    const float4* wp = (const float4*)(cw + (size_t)c * 9);
#pragma unroll
    for (int i = 0; i < 9; ++i) *(float4*)(w36 + i * 4) = wp[i];

    float a0 = 0.f, a1 = 0.f, a2 = 0.f, a3 = 0.f;
#pragma unroll
    for (int dy = -1; dy <= 1; ++dy) {
      int ny = yy + dy;
      if ((unsigned)ny < 32u) {
#pragma unroll
        for (int dx = -1; dx <= 1; ++dx) {
          int nx = xx + dx;
          if ((unsigned)nx < 32u) {
            ushort4 v = *(const ushort4*)(xb + (size_t)(ny * 32 + nx) * 768 + c);
            const int j = (dy + 1) * 3 + (dx + 1);
            a0 += w36[0 * 9 + j] * bf2f(v.x);
            a1 += w36[1 * 9 + j] * bf2f(v.y);
            a2 += w36[2 * 9 + j] * bf2f(v.z);
            a3 += w36[3 * 9 + j] * bf2f(v.w);
          }
        }
      }
    }
    ushort4 f = *(const ushort4*)(yp + (size_t)m * 768 + c);
    yv[g][0] = bf2f(f.x) + 0.1f * a0;
    yv[g][1] = bf2f(f.y) + 0.1f * a1;
    yv[g][2] = bf2f(f.z) + 0.1f * a2;
    yv[g][3] = bf2f(f.w) + 0.1f * a3;
  }

  float s1 = 0.f, s2 = 0.f;
#pragma unroll
  for (int g = 0; g < 3; ++g)
#pragma unroll
    for (int e = 0; e < 4; ++e) { s1 += yv[g][e]; s2 += yv[g][e] * yv[g][e]; }
#pragma unroll
  for (int off = 32; off; off >>= 1) {
    s1 += __shfl_xor(s1, off, 64);
    s2 += __shfl_xor(s2, off, 64);
  }
  const float mu = s1 * (1.f / 768.f);
  const float var = s2 * (1.f / 768.f) - mu * mu;
  const float rs = rsqrtf(var + 1e-5f);

#pragma unroll
  for (int g = 0; g < 3; ++g) {
    const int c = g * 256 + lane * 4;
    float4 gm = *(const float4*)(gamma + c);
    float4 bt = *(const float4*)(beta + c);
    float4 o;
    o.x = (yv[g][0] - mu) * rs * gm.x + bt.x;
    o.y = (yv[g][1] - mu) * rs * gm.y + bt.y;
    o.z = (yv[g][2] - mu) * rs * gm.z + bt.z;
    o.w = (yv[g][3] - mu) * rs * gm.w + bt.w;
    *(float4*)(out + (size_t)m * 768 + c) = o;
  }
}

// ---------- host ----------
extern "C" void kernel_launch(void* const* d_in, const int* in_sizes, int n_in,
                              void* d_out, int out_size, void* d_ws, size_t ws_size,
                              hipStream_t stream) {
  const float* x     = (const float*)d_in[0];
  const float* wqkv  = (const float*)d_in[1];
  const float* wproj = (const float*)d_in[2];
  const float* temp  = (const float*)d_in[3];
  const float* cw    = (const float*)d_in[4];
  const float* gamma = (const float*)d_in[5];
  const float* beta  = (const float*)d_in[6];
  float* out = (float*)d_out;
  char* ws = (char*)d_ws;

  // workspace layout (~113.7 MiB; aliased regions are stream-ordered dead)
  unsigned short* xb    = (unsigned short*)(ws);               // 25165824 (live to k_final)
  unsigned short* wqb   = (unsigned short*)(ws + 25165824);    // 3538944 (dead after kg0)
  unsigned short* qT    = (unsigned short*)(ws + 28704768);    // 25165824 (dead after k_qk)
  unsigned short* yp    = qT;                                  //   alias (kg1->final)
  unsigned short* kT    = (unsigned short*)(ws + 53870592);    // 25165824 (dead after k_qk)
  unsigned short* B_all = kT;                                  //   alias (prep->kg1)
  unsigned short* vP    = (unsigned short*)(ws + 79036416);    // 25165824 (kg0->kg1)
  float* ns             = (float*)(ws + 104202240);            // 98304 (k_qk atomics -> prep)
  float* PA             = (float*)(ws + 104300544);            // 9437184 (k_qk -> prep)

  k_cvt2<<<dim3(2305), dim3(256), 0, stream>>>(x, xb, 16384 * 768 / 4,
                                               wqkv, wqb, 2304 * 768 / 4, ns);
  kg0_qkv<<<dim3(1536), dim3(512), 0, stream>>>(xb, wqb, qT, kT, vP);
  k_qk<<<dim3(256), dim3(256), 0, stream>>>(qT, kT, PA, ns);
  k_prep<<<dim3(512), dim3(256), 0, stream>>>(PA, ns, temp, wproj, B_all);
  kg1_proj<<<dim3(512), dim3(512), 0, stream>>>(vP, B_all, yp);
  k_final<<<dim3(4096), dim3(256), 0, stream>>>(yp, xb, cw, gamma, beta, out);
}

// Round 16
// 185.248 us; speedup vs baseline: 1.2884x; 1.0466x over previous
//
#include <hip/hip_runtime.h>

#define DEVI __device__ __forceinline__

typedef __bf16 bf16x8 __attribute__((ext_vector_type(8)));
typedef float f32x4 __attribute__((ext_vector_type(4)));

// ---------- small helpers ----------
DEVI unsigned short f2bf(float f) {
  unsigned u = __builtin_bit_cast(unsigned, f);
  u += 0x7FFFu + ((u >> 16) & 1u);   // RNE
  return (unsigned short)(u >> 16);
}
DEVI float bf2f(unsigned short s) {
  return __builtin_bit_cast(float, ((unsigned)s) << 16);
}
DEVI f32x4 mfma16(bf16x8 a, bf16x8 b, f32x4 c) {
  return __builtin_amdgcn_mfma_f32_16x16x32_bf16(a, b, c, 0, 0, 0);
}
DEVI void gload16(const void* g, void* l) {
  __builtin_amdgcn_global_load_lds(
      (const __attribute__((address_space(1))) void*)g,
      (__attribute__((address_space(3))) void*)l, 16, 0, 0);
}
// LDS fragment read, rows ROWB bytes, XOR-swizzle byte ^= (row&7)<<4
template <int ROWB>
DEVI bf16x8 frag_ld(const char* lds, int row, int kb) {
  int off = row * ROWB + (kb ^ ((row & 7) << 4));
  return __builtin_bit_cast(bf16x8, *(const uint4*)(lds + off));
}
DEVI float ssq8(uint4 u) {
  unsigned a[4] = {u.x, u.y, u.z, u.w};
  float s = 0.f;
#pragma unroll
  for (int i = 0; i < 4; ++i) {
    float lo = __builtin_bit_cast(float, a[i] << 16);
    float hi = __builtin_bit_cast(float, a[i] & 0xFFFF0000u);
    s += lo * lo + hi * hi;
  }
  return s;
}
DEVI float ssqbf8(bf16x8 v) { return ssq8(__builtin_bit_cast(uint4, v)); }

// ---------- fp32 -> bf16 convert (+ ns zeroing in block 2304) ----------
__global__ __launch_bounds__(256) void k_cvt2(const float* __restrict__ a,
                                              unsigned short* __restrict__ oa, int n4a,
                                              const float* __restrict__ b,
                                              unsigned short* __restrict__ ob, int n4b,
                                              float* __restrict__ ns) {
  const int tid = threadIdx.x;
  if (blockIdx.x < 2048) {
    const int chunk = (blockIdx.x & 7) * 256 + (blockIdx.x >> 3);  // bijective [0,2048)
    const int i0 = chunk * 1536;                                   // 1536 float4 = 8 rows
    for (int i = i0 + tid; i < i0 + 1536; i += 256) {
      float4 f = ((const float4*)a)[i];
      ushort4 o;
      o.x = f2bf(f.x); o.y = f2bf(f.y); o.z = f2bf(f.z); o.w = f2bf(f.w);
      ((ushort4*)oa)[i] = o;
    }
  } else if (blockIdx.x < 2304) {
    for (int i = (blockIdx.x - 2048) * 256 + tid; i < n4b; i += 256 * 256) {
      float4 f = ((const float4*)b)[i];
      ushort4 o;
      o.x = f2bf(f.x); o.y = f2bf(f.y); o.z = f2bf(f.z); o.w = f2bf(f.w);
      ((ushort4*)ob)[i] = o;
    }
  } else {
    float4 z = {0.f, 0.f, 0.f, 0.f};
    for (int i = tid; i < 6144; i += 256) ((float4*)ns)[i] = z;  // 24576 floats
  }
}

// ---------- pipelined 128x192 GEMM body (BK=64, 8 waves 2Mx4N, 2 blocks/CU) ----------
// MODE 0: qkv = x@wqkv^T, grid 1536 (128mt x 12jt = 3 rounds); ALL outputs via
//         LDS-transpose, fully coalesced rows (q/k: 256B rows; v: 384B rows).
// MODE 1: yp  = vP@B_b^T, grid 512, LDS-transposed coalesced bf16 -> yp
template <int MODE>
DEVI void gemm_body(char* lds, const unsigned short* __restrict__ A,
                    const unsigned short* __restrict__ B0,
                    unsigned short* __restrict__ o0, unsigned short* __restrict__ o1,
                    unsigned short* __restrict__ o2) {
  const int tid = threadIdx.x, l = tid & 63, wid = tid >> 6;
  const int wr = wid >> 2, wc = wid & 3;
  const int xg = blockIdx.x;
  const int CPX = MODE ? 64 : 192;
  const int NJT = MODE ? 4 : 12;
  const int li = (xg & 7) * CPX + (xg >> 3);
  const int jt = li % NJT, mt = li / NJT;
  const int m0 = mt * 128, j0 = jt * 192;
  const unsigned short* Bb = MODE ? B0 + (size_t)(m0 >> 10) * 589824 : B0;

  const unsigned short* srcg[4][2];
  int ldso[4][2];
#pragma unroll
  for (int sg = 0; sg < 4; ++sg) {
    const bool isA = (sg == 0) || (sg == 3);
#pragma unroll
    for (int i = 0; i < 2; ++i) {
      int c;
      if (sg == 0)      c = (wid < 4) ? wid : wid + 4;
      else if (sg == 3) c = (wid < 4) ? wid + 4 : wid + 8;
      else if (sg == 1) { int cc = 2 * wid + i; c = (cc >> 2) * 6 + (cc & 3); }
      else              c = (wid >> 1) * 6 + 4 + (wid & 1);
      const int r0 = 8 * c;
      const int r = r0 + (l >> 3);
      const int scol = ((l & 7) ^ (l >> 3)) << 3;
      srcg[sg][i] = (isA ? A + (size_t)(m0 + r) * 768 : Bb + (size_t)(j0 + r) * 768) + scol;
      ldso[sg][i] = (isA ? 0 : 16384) + r0 * 128;
    }
  }
  const int swz = (l & 7) << 4;
  const int uu = (l >> 4) << 4;
  const int c0 = uu ^ swz;
  const int c1 = (64 | uu) ^ swz;
  const int arow = (wr * 64 + (l & 15)) * 128;
  const int brow = 16384 + (wc * 48 + (l & 15)) * 128;

  f32x4 acc[4][3];
#pragma unroll
  for (int i = 0; i < 4; ++i)
#pragma unroll
    for (int j = 0; j < 3; ++j)
#pragma unroll
      for (int e = 0; e < 4; ++e) acc[i][j][e] = 0.f;
  bf16x8 a[2][2], a2[2][2], b01[2][2], b2[2];

#define STAGE1(sg, nxt, ko) \
  gload16(srcg[sg][0] + (ko), lds + (nxt)*40960 + ldso[sg][0])
#define STAGE2(sg, nxt, ko)                                        \
  do {                                                             \
    gload16(srcg[sg][0] + (ko), lds + (nxt)*40960 + ldso[sg][0]);  \
    gload16(srcg[sg][1] + (ko), lds + (nxt)*40960 + ldso[sg][1]);  \
  } while (0)
#define LD128(off) __builtin_bit_cast(bf16x8, *(const uint4*)(cb_ + (off)))

  STAGE1(0, 0, 0); STAGE2(1, 0, 0); STAGE1(2, 0, 0); STAGE1(3, 0, 0);
  asm volatile("s_waitcnt vmcnt(2)" ::: "memory");
  __builtin_amdgcn_s_barrier();

#define KBODY(KT, LASTF)                                                              \
  {                                                                                   \
    const char* cb_ = lds + ((KT) & 1) * 40960;                                       \
    const int nxt = (((KT) & 1) ^ 1);                                                 \
    const int ko = ((KT) + 1) * 64;                                                   \
    _Pragma("unroll") for (int mf = 0; mf < 2; ++mf) {                                \
      a[mf][0] = LD128(arow + mf * 2048 + c0);                                        \
      a[mf][1] = LD128(arow + mf * 2048 + c1);                                        \
    }                                                                                 \
    _Pragma("unroll") for (int nf = 0; nf < 2; ++nf) {                                \
      b01[nf][0] = LD128(brow + nf * 2048 + c0);                                      \
      b01[nf][1] = LD128(brow + nf * 2048 + c1);                                      \
    }                                                                                 \
    if (!(LASTF)) {                                                                   \
      STAGE1(0, nxt, ko); STAGE2(1, nxt, ko);                                         \
      asm volatile("s_waitcnt vmcnt(3)" ::: "memory");                                \
    } else {                                                                          \
      asm volatile("s_waitcnt vmcnt(0)" ::: "memory");                                \
    }                                                                                 \
    __builtin_amdgcn_s_barrier();                                                     \
    __builtin_amdgcn_s_setprio(1);                                                    \
    _Pragma("unroll") for (int mf = 0; mf < 2; ++mf)                                  \
      _Pragma("unroll") for (int nf = 0; nf < 2; ++nf) {                              \
        acc[mf][nf] = mfma16(a[mf][0], b01[nf][0], acc[mf][nf]);                      \
        acc[mf][nf] = mfma16(a[mf][1], b01[nf][1], acc[mf][nf]);                      \
      }                                                                               \
    __builtin_amdgcn_s_setprio(0);                                                    \
    b2[0] = LD128(brow + 2 * 2048 + c0);                                              \
    b2[1] = LD128(brow + 2 * 2048 + c1);                                              \
    _Pragma("unroll") for (int mf = 0; mf < 2; ++mf) {                                \
      a2[mf][0] = LD128(arow + (mf + 2) * 2048 + c0);                                 \
      a2[mf][1] = LD128(arow + (mf + 2) * 2048 + c1);                                 \
    }                                                                                 \
    if (!(LASTF)) {                                                                   \
      STAGE1(2, nxt, ko); STAGE1(3, nxt, ko);                                        \
      asm volatile("s_waitcnt vmcnt(2)" ::: "memory");                                \
    }                                                                                 \
    __builtin_amdgcn_s_barrier();                                                     \
    __builtin_amdgcn_s_setprio(1);                                                    \
    _Pragma("unroll") for (int mf = 0; mf < 2; ++mf) {                                \
      acc[mf][2] = mfma16(a[mf][0], b2[0], acc[mf][2]);                               \
      acc[mf][2] = mfma16(a[mf][1], b2[1], acc[mf][2]);                               \
    }                                                                                 \
    _Pragma("unroll") for (int mf = 0; mf < 2; ++mf)                                  \
      _Pragma("unroll") for (int nf = 0; nf < 2; ++nf) {                              \
        acc[mf + 2][nf] = mfma16(a2[mf][0], b01[nf][0], acc[mf + 2][nf]);             \
        acc[mf + 2][nf] = mfma16(a2[mf][1], b01[nf][1], acc[mf + 2][nf]);             \
      }                                                                               \
    _Pragma("unroll") for (int mf = 0; mf < 2; ++mf) {                                \
      acc[mf + 2][2] = mfma16(a2[mf][0], b2[0], acc[mf + 2][2]);                      \
      acc[mf + 2][2] = mfma16(a2[mf][1], b2[1], acc[mf + 2][2]);                      \
    }                                                                                 \
    __builtin_amdgcn_s_setprio(0);                                                    \
  }

#pragma unroll 1
  for (int kt = 0; kt < 11; ++kt) KBODY(kt, false);
  KBODY(11, true);
#undef KBODY
#undef STAGE2
#undef STAGE1
#undef LD128

  const int s = MODE ? 3 : (j0 / 768);
  if (MODE == 0 && s < 2) {
    unsigned short* t = (unsigned short*)lds;
    unsigned short* base = (s == 0) ? o0 : o1;
    const int nl0 = wr * 64 + ((l >> 4) << 2);   // n-local
    const int cl0 = wc * 48 + (l & 15);          // j-local
#pragma unroll
    for (int mf = 0; mf < 4; ++mf)
#pragma unroll
      for (int nf = 0; nf < 3; ++nf)
#pragma unroll
        for (int rr = 0; rr < 4; ++rr)
          t[(cl0 + nf * 16) * 136 + nl0 + mf * 16 + rr] = f2bf(acc[mf][nf][rr]);
    asm volatile("s_waitcnt lgkmcnt(0)" ::: "memory");
    __builtin_amdgcn_s_barrier();
    const int bb = m0 >> 10;
    const int nin = m0 & 1023;
    const int jb = j0 % 768;
    for (int i2 = tid; i2 < 3072; i2 += 512) {   // 192 rows x 16 chunks of 16B
      int r = i2 >> 4, ch = i2 & 15;
      int jj = jb + r;
      int hh = jj / 96, dd = jj % 96;
      uint4 u = *(const uint4*)(t + r * 136 + ch * 8);
      *(uint4*)(base + ((size_t)((bb * 8 + hh) * 96 + dd)) * 1024 + nin + ch * 8) = u;
    }
  } else {
    unsigned short* dst = MODE ? o0 : o2;
    const int colb = MODE ? j0 : (j0 - 1536);
    unsigned short* t = (unsigned short*)lds;   // [128][200]
    const int nl0 = wr * 64 + ((l >> 4) << 2);
    const int cl0 = wc * 48 + (l & 15);
#pragma unroll
    for (int mf = 0; mf < 4; ++mf)
#pragma unroll
      for (int nf = 0; nf < 3; ++nf)
#pragma unroll
        for (int rr = 0; rr < 4; ++rr)
          t[(nl0 + mf * 16 + rr) * 200 + cl0 + nf * 16] = f2bf(acc[mf][nf][rr]);
    asm volatile("s_waitcnt lgkmcnt(0)" ::: "memory");
    __builtin_amdgcn_s_barrier();
    for (int i2 = tid; i2 < 3072; i2 += 512) {
      int r = i2 / 24, ch = i2 % 24;
      uint4 u = *(const uint4*)(t + r * 200 + ch * 8);
      *(uint4*)(dst + (size_t)(m0 + r) * 768 + colb + ch * 8) = u;
    }
  }
}

__global__ __launch_bounds__(512, 4) void kg0_qkv(const unsigned short* __restrict__ A,
                                                  const unsigned short* __restrict__ B0,
                                                  unsigned short* __restrict__ o0,
                                                  unsigned short* __restrict__ o1,
                                                  unsigned short* __restrict__ o2) {
  __shared__ alignas(16) char lds[81920];
  gemm_body<0>(lds, A, B0, o0, o1, o2);
}
__global__ __launch_bounds__(512, 4) void kg1_proj(const unsigned short* __restrict__ A,
                                                   const unsigned short* __restrict__ B0,
                                                   unsigned short* __restrict__ o0) {
  __shared__ alignas(16) char lds[81920];
  gemm_body<1>(lds, A, B0, o0, nullptr, nullptr);
}

// ---------- k_qk: partial A' = q^T k over a K-half -> PA fp32; + ssq atomics ----------
// grid 256 = (bh, kh); 4-buffer pipeline, counted vmcnt(6), 1 barrier/iter.
// Skew safety: 4 bufs + 1 barrier/iter => writer/reader buffers always distinct.
__global__ __launch_bounds__(256) void k_qk(const unsigned short* __restrict__ qT,
                                            const unsigned short* __restrict__ kT,
                                            float* __restrict__ PA,
                                            float* __restrict__ ns) {
  __shared__ alignas(16) char lQK[4][24576];   // per buf: q [96][64] @0, k @12288
  const int blk = blockIdx.x, tid = threadIdx.x, lane = tid & 63, wid = tid >> 6;
  const int bh = blk >> 1, kh = blk & 1;
  const int wr = wid >> 1, wc = wid & 1;
  const unsigned short* qb = qT + (size_t)bh * 96 * 1024 + kh * 512;
  const unsigned short* kb = kT + (size_t)bh * 96 * 1024 + kh * 512;

  const unsigned short* srcp[6];
  int dsto[6];
#pragma unroll
  for (int i = 0; i < 6; ++i) {
    int cid = wid * 6 + i;          // 24 chunks: 12 q + 12 k
    bool isK = cid >= 12;
    int c = isK ? cid - 12 : cid;
    int p = c * 1024 + lane * 16;
    int r = p >> 7, cb = p & 127;
    int cbs = cb ^ ((r & 7) << 4);
    srcp[i] = (isK ? kb : qb) + (size_t)r * 1024 + (cbs >> 1);
    dsto[i] = (isK ? 12288 : 0) + c * 1024;
  }

  f32x4 acc[3][3];
#pragma unroll
  for (int i = 0; i < 3; ++i)
#pragma unroll
    for (int j = 0; j < 3; ++j)
#pragma unroll
      for (int e = 0; e < 4; ++e) acc[i][j][e] = 0.f;
  float sq[3] = {0.f, 0.f, 0.f}, sk[3] = {0.f, 0.f, 0.f};

  // prologue: stage kt0 and kt1 (12 loads outstanding)
#pragma unroll
  for (int i = 0; i < 6; ++i) gload16(srcp[i], lQK[0] + dsto[i]);
#pragma unroll
  for (int i = 0; i < 6; ++i) gload16(srcp[i] + 64, lQK[1] + dsto[i]);

#pragma unroll 1
  for (int kt = 0; kt < 8; ++kt) {
    asm volatile("s_waitcnt vmcnt(6)" ::: "memory");   // kt's 6 loads landed
    __builtin_amdgcn_s_barrier();
    if (kt < 6) {
      char* nb = lQK[(kt + 2) & 3];
      const int ko = (kt + 2) * 64;
#pragma unroll
      for (int i = 0; i < 6; ++i) gload16(srcp[i] + ko, nb + dsto[i]);
    }
    const char* bq = lQK[kt & 3];
#pragma unroll
    for (int ks = 0; ks < 2; ++ks) {
      const int kb2 = ks * 64 + ((lane >> 4) << 4);
      bf16x8 af[3], bfv[3];
#pragma unroll
      for (int mb = 0; mb < 3; ++mb) af[mb] = frag_ld<128>(bq, wr * 48 + mb * 16 + (lane & 15), kb2);
#pragma unroll
      for (int nb2 = 0; nb2 < 3; ++nb2) bfv[nb2] = frag_ld<128>(bq + 12288, wc * 48 + nb2 * 16 + (lane & 15), kb2);
      if (wc == 0) {
#pragma unroll
        for (int mb = 0; mb < 3; ++mb) sq[mb] += ssqbf8(af[mb]);
      }
      if (wr == 0) {
#pragma unroll
        for (int nb2 = 0; nb2 < 3; ++nb2) sk[nb2] += ssqbf8(bfv[nb2]);
      }
#pragma unroll
      for (int mb = 0; mb < 3; ++mb)
#pragma unroll
        for (int nb2 = 0; nb2 < 3; ++nb2) acc[mb][nb2] = mfma16(af[mb], bfv[nb2], acc[mb][nb2]);
    }
  }

  float* pa = PA + (size_t)(bh * 2 + kh) * 9216;
  const int rb = wr * 48 + ((lane >> 4) << 2);
  const int eb = wc * 48 + (lane & 15);
#pragma unroll
  for (int mb = 0; mb < 3; ++mb)
#pragma unroll
    for (int nb = 0; nb < 3; ++nb)
#pragma unroll
      for (int rr = 0; rr < 4; ++rr)
        pa[(rb + mb * 16 + rr) * 96 + eb + nb * 16] = acc[mb][nb][rr];

  if (wc == 0) {
#pragma unroll
    for (int mb = 0; mb < 3; ++mb) {
      float s = sq[mb];
      s += __shfl_xor(s, 16, 64);
      s += __shfl_xor(s, 32, 64);
      if ((lane >> 4) == 0)
        atomicAdd(&ns[bh * 96 + wr * 48 + mb * 16 + (lane & 15)], s);
    }
  }
  if (wr == 0) {
#pragma unroll
    for (int nb2 = 0; nb2 < 3; ++nb2) {
      float s = sk[nb2];
      s += __shfl_xor(s, 16, 64);
      s += __shfl_xor(s, 32, 64);
      if ((lane >> 4) == 0)
        atomicAdd(&ns[12288 + bh * 96 + wc * 48 + nb2 * 16 + (lane & 15)], s);
    }
  }
}

// ---------- fused softmax + B-prep: B_h = softmax(A'_h)^T @ W_h^T ----------
__global__ __launch_bounds__(256) void k_prep(const float* __restrict__ PA,
                                              const float* __restrict__ ns,
                                              const float* __restrict__ temp,
                                              const float* __restrict__ wproj,
                                              unsigned short* __restrict__ B_all) {
  __shared__ alignas(16) char pl[19968 + 39936];   // lPt [96][104] | scratch (aa / lW)
  unsigned short* lPt = (unsigned short*)pl;
  float* aa = (float*)(pl + 19968);                // [96][96] fp32
  unsigned short* lW = (unsigned short*)(pl + 19968);  // [192][104] bf16
  unsigned short* tr = lW;                         // aliased after MFMA ([192][100])
  __shared__ float lrq[96], lrk[96];
  const int blk = blockIdx.x;
  const int idx = blk >> 3;
  const int b = (blk & 7) * 2 + (idx >> 5);
  const int h = (idx >> 2) & 7, cq = idx & 3;
  const int bh = b * 8 + h;
  const int tid = threadIdx.x, l = tid & 63, wid = tid >> 6;
  const int wr = wid >> 1, wc = wid & 1;
  const float invt = 1.f / temp[h];

  if (tid < 96)       lrq[tid] = 1.f / fmaxf(sqrtf(ns[bh * 96 + tid]), 1e-12f);
  else if (tid < 192) lrk[tid - 96] = 1.f / fmaxf(sqrtf(ns[12288 + bh * 96 + tid - 96]), 1e-12f);

  const float4* pp = (const float4*)(PA + (size_t)bh * 2 * 9216);
  for (int i = tid; i < 2304; i += 256) {
    float4 x0 = pp[i], x1 = pp[i + 2304];
    float4 r;
    r.x = x0.x + x1.x; r.y = x0.y + x1.y; r.z = x0.z + x1.z; r.w = x0.w + x1.w;
    ((float4*)aa)[i] = r;
  }
  __syncthreads();

  for (int d = wid; d < 96; d += 4) {
    float v0 = aa[d * 96 + l] * lrq[d] * lrk[l] * invt;
    float v1 = (l < 32) ? aa[d * 96 + 64 + l] * lrq[d] * lrk[64 + l] * invt : -3.0e38f;
    float mx = fmaxf(v0, v1);
#pragma unroll
    for (int off = 32; off; off >>= 1) mx = fmaxf(mx, __shfl_xor(mx, off, 64));
    float p0 = __expf(v0 - mx);
    float p1 = (l < 32) ? __expf(v1 - mx) : 0.f;
    float ssum = p0 + p1;
#pragma unroll
    for (int off = 32; off; off >>= 1) ssum += __shfl_xor(ssum, off, 64);
    float rs = 1.f / ssum;
    lPt[l * 104 + d] = f2bf(p0 * rs);                 // lPt[e][d]
    if (l < 32) lPt[(64 + l) * 104 + d] = f2bf(p1 * rs);
  }
  __syncthreads();                 // aa dead; lW may overwrite scratch

  for (int i2 = tid; i2 < 4608; i2 += 256) {
    int r = i2 / 24, ch = i2 % 24;
    float4 f = *(const float4*)(wproj + (size_t)(cq * 192 + r) * 768 + h * 96 + ch * 4);
    ushort4 o;
    o.x = f2bf(f.x); o.y = f2bf(f.y); o.z = f2bf(f.z); o.w = f2bf(f.w);
    *(ushort4*)(lW + r * 104 + ch * 4) = o;
  }
  __syncthreads();

  f32x4 acc[3][6];
#pragma unroll
  for (int i = 0; i < 3; ++i)
#pragma unroll
    for (int j = 0; j < 6; ++j)
#pragma unroll
      for (int e = 0; e < 4; ++e) acc[i][j][e] = 0.f;

#pragma unroll
  for (int ks = 0; ks < 3; ++ks) {
    const int kof = ks * 32 + ((l >> 4) << 3);
    bf16x8 af[3], bv[6];
#pragma unroll
    for (int mb = 0; mb < 3; ++mb)
      af[mb] = __builtin_bit_cast(bf16x8, *(const uint4*)(lPt + (wr * 48 + mb * 16 + (l & 15)) * 104 + kof));
#pragma unroll
    for (int nb = 0; nb < 6; ++nb)
      bv[nb] = __builtin_bit_cast(bf16x8, *(const uint4*)(lW + (wc * 96 + nb * 16 + (l & 15)) * 104 + kof));
#pragma unroll
    for (int mb = 0; mb < 3; ++mb)
#pragma unroll
      for (int nb = 0; nb < 6; ++nb) acc[mb][nb] = mfma16(af[mb], bv[nb], acc[mb][nb]);
  }

  __syncthreads();                 // all lW reads done; safe to alias as tr
  const int e0 = wr * 48 + ((l >> 4) << 2);
  const int cl0 = wc * 96 + (l & 15);
#pragma unroll
  for (int mb = 0; mb < 3; ++mb)
#pragma unroll
    for (int nb = 0; nb < 6; ++nb) {
      ushort4 pk;
      pk.x = f2bf(acc[mb][nb][0]); pk.y = f2bf(acc[mb][nb][1]);
      pk.z = f2bf(acc[mb][nb][2]); pk.w = f2bf(acc[mb][nb][3]);
      *(ushort4*)(tr + (cl0 + nb * 16) * 100 + e0 + mb * 16) = pk;
    }
  __syncthreads();
  for (int i2 = tid; i2 < 2304; i2 += 256) {
    int r = i2 / 12, ch = i2 % 12;
    uint4 u = *(const uint4*)(tr + r * 100 + ch * 8);
    *(uint4*)(B_all + ((size_t)(b * 768) + cq * 192 + r) * 768 + h * 96 + ch * 8) = u;
  }
}

// ---------- final: y = yp(bf16) + 0.1*dwconv3x3(xb bf16); LayerNorm ----------
// 2 tokens per wave (w36 conv weights amortized, 2x ILP); grid 2048.
__global__ __launch_bounds__(256) void k_final(const unsigned short* __restrict__ yp,
                                               const unsigned short* __restrict__ xb16,
                                               const float* __restrict__ cw,
                                               const float* __restrict__ gamma,
                                               const float* __restrict__ beta,
                                               float* __restrict__ out) {
  const int wid = threadIdx.x >> 6, lane = threadIdx.x & 63;
  const int mb0 = (blockIdx.x & 7) * 2048 + (blockIdx.x >> 3) * 8 + wid * 2;

  float yv[2][3][4];
#pragma unroll
  for (int g = 0; g < 3; ++g) {
    const int c = g * 256 + lane * 4;
    float w36[36];
    const float4* wp = (const float4*)(cw + (size_t)c * 9);
#pragma unroll
    for (int i = 0; i < 9; ++i) *(float4*)(w36 + i * 4) = wp[i];

#pragma unroll
    for (int t = 0; t < 2; ++t) {
      const int m = mb0 + t;
      const int bb = m >> 10, n = m & 1023, yy = n >> 5, xx = n & 31;
      const unsigned short* xb = xb16 + (size_t)bb * 1024 * 768;
      float a0 = 0.f, a1 = 0.f, a2 = 0.f, a3 = 0.f;
#pragma unroll
      for (int dy = -1; dy <= 1; ++dy) {
        int ny = yy + dy;
        if ((unsigned)ny < 32u) {
#pragma unroll
          for (int dx = -1; dx <= 1; ++dx) {
            int nx = xx + dx;
            if ((unsigned)nx < 32u) {
              ushort4 v = *(const ushort4*)(xb + (size_t)(ny * 32 + nx) * 768 + c);
              const int j = (dy + 1) * 3 + (dx + 1);
              a0 += w36[0 * 9 + j] * bf2f(v.x);
              a1 += w36[1 * 9 + j] * bf2f(v.y);
              a2 += w36[2 * 9 + j] * bf2f(v.z);
              a3 += w36[3 * 9 + j] * bf2f(v.w);
            }
          }
        }
      }
      ushort4 f = *(const ushort4*)(yp + (size_t)m * 768 + c);
      yv[t][g][0] = bf2f(f.x) + 0.1f * a0;
      yv[t][g][1] = bf2f(f.y) + 0.1f * a1;
      yv[t][g][2] = bf2f(f.z) + 0.1f * a2;
      yv[t][g][3] = bf2f(f.w) + 0.1f * a3;
    }
  }

#pragma unroll
  for (int t = 0; t < 2; ++t) {
    float s1 = 0.f, s2 = 0.f;
#pragma unroll
    for (int g = 0; g < 3; ++g)
#pragma unroll
      for (int e = 0; e < 4; ++e) { s1 += yv[t][g][e]; s2 += yv[t][g][e] * yv[t][g][e]; }
#pragma unroll
    for (int off = 32; off; off >>= 1) {
      s1 += __shfl_xor(s1, off, 64);
      s2 += __shfl_xor(s2, off, 64);
    }
    const float mu = s1 * (1.f / 768.f);
    const float var = s2 * (1.f / 768.f) - mu * mu;
    const float rs = rsqrtf(var + 1e-5f);
    const int m = mb0 + t;
#pragma unroll
    for (int g = 0; g < 3; ++g) {
      const int c = g * 256 + lane * 4;
      float4 gm = *(const float4*)(gamma + c);
      float4 bt = *(const float4*)(beta + c);
      float4 o;
      o.x = (yv[t][g][0] - mu) * rs * gm.x + bt.x;
      o.y = (yv[t][g][1] - mu) * rs * gm.y + bt.y;
      o.z = (yv[t][g][2] - mu) * rs * gm.z + bt.z;
      o.w = (yv[t][g][3] - mu) * rs * gm.w + bt.w;
      *(float4*)(out + (size_t)m * 768 + c) = o;
    }
  }
}

// ---------- host ----------
extern "C" void kernel_launch(void* const* d_in, const int* in_sizes, int n_in,
                              void* d_out, int out_size, void* d_ws, size_t ws_size,
                              hipStream_t stream) {
  const float* x     = (const float*)d_in[0];
  const float* wqkv  = (const float*)d_in[1];
  const float* wproj = (const float*)d_in[2];
  const float* temp  = (const float*)d_in[3];
  const float* cw    = (const float*)d_in[4];
  const float* gamma = (const float*)d_in[5];
  const float* beta  = (const float*)d_in[6];
  float* out = (float*)d_out;
  char* ws = (char*)d_ws;

  // workspace layout (~113.7 MiB; aliased regions are stream-ordered dead)
  unsigned short* xb    = (unsigned short*)(ws);               // 25165824 (live to k_final)
  unsigned short* wqb   = (unsigned short*)(ws + 25165824);    // 3538944 (dead after kg0)
  unsigned short* qT    = (unsigned short*)(ws + 28704768);    // 25165824 (dead after k_qk)
  unsigned short* yp    = qT;                                  //   alias (kg1->final)
  unsigned short* kT    = (unsigned short*)(ws + 53870592);    // 25165824 (dead after k_qk)
  unsigned short* B_all = kT;                                  //   alias (prep->kg1)
  unsigned short* vP    = (unsigned short*)(ws + 79036416);    // 25165824 (kg0->kg1)
  float* ns             = (float*)(ws + 104202240);            // 98304 (k_qk atomics -> prep)
  float* PA             = (float*)(ws + 104300544);            // 9437184 (k_qk -> prep)

  k_cvt2<<<dim3(2305), dim3(256), 0, stream>>>(x, xb, 16384 * 768 / 4,
                                               wqkv, wqb, 2304 * 768 / 4, ns);
  kg0_qkv<<<dim3(1536), dim3(512), 0, stream>>>(xb, wqb, qT, kT, vP);
  k_qk<<<dim3(256), dim3(256), 0, stream>>>(qT, kT, PA, ns);
  k_prep<<<dim3(512), dim3(256), 0, stream>>>(PA, ns, temp, wproj, B_all);
  kg1_proj<<<dim3(512), dim3(512), 0, stream>>>(vP, B_all, yp);
  k_final<<<dim3(2048), dim3(256), 0, stream>>>(yp, xb, cw, gamma, beta, out);
}